// Round 1
// baseline (614.395 us; speedup 1.0000x reference)
//
#include <hip/hip_runtime.h>
#include <math.h>

#define NPTS 4096
#define NB 2

// ---------------- GEMM f32: Y[b] = W(MxK) @ X[b](KxN), N=4096 ----------------
__global__ __launch_bounds__(256)
void gemm_f32(const float* __restrict__ W, const float* __restrict__ X,
              float* __restrict__ Y, int M, int K) {
  const int NN = NPTS;
  __shared__ float Ws[16][68];   // [kk][mm], padded to 68 to soften bank conflicts
  __shared__ float Xs[16][64];   // [kk][nn]
  int b  = blockIdx.z;
  int n0 = blockIdx.x * 64;
  int m0 = blockIdx.y * 64;
  int tid = threadIdx.x;
  int tx = tid & 15, ty = tid >> 4;
  const float* Xb = X + (size_t)b * K * NN;
  float*       Yb = Y + (size_t)b * M * NN;
  float c[4][4] = {{0.f}};
  int ktiles = (K + 15) >> 4;
  for (int kt = 0; kt < ktiles; ++kt) {
    int k0 = kt << 4;
    // stage W tile: Ws[kk][mm] = W[m0+mm][k0+kk]
    {
      int kk = tx;
      #pragma unroll
      for (int i = 0; i < 4; ++i) {
        int mm = ty * 4 + i;
        int gm = m0 + mm, gk = k0 + kk;
        float v = 0.f;
        if (gm < M && gk < K) v = W[(size_t)gm * K + gk];
        Ws[kk][mm] = v;
      }
    }
    // stage X tile: Xs[kk][nn] = X[k0+kk][n0+nn]
    {
      int nn = tid & 63;
      int kb = (tid >> 6) * 4;
      #pragma unroll
      for (int i = 0; i < 4; ++i) {
        int kk2 = kb + i;
        int gk = k0 + kk2;
        float v = 0.f;
        if (gk < K) v = Xb[(size_t)gk * NN + n0 + nn];
        Xs[kk2][nn] = v;
      }
    }
    __syncthreads();
    #pragma unroll
    for (int kk = 0; kk < 16; ++kk) {
      float4 a4 = *(const float4*)&Ws[kk][ty * 4];
      float4 b4 = *(const float4*)&Xs[kk][tx * 4];
      float av[4] = {a4.x, a4.y, a4.z, a4.w};
      float bv[4] = {b4.x, b4.y, b4.z, b4.w};
      #pragma unroll
      for (int i = 0; i < 4; ++i)
        #pragma unroll
        for (int j = 0; j < 4; ++j)
          c[i][j] = fmaf(av[i], bv[j], c[i][j]);
    }
    __syncthreads();
  }
  #pragma unroll
  for (int i = 0; i < 4; ++i) {
    int gm = m0 + ty * 4 + i;
    if (gm < M) {
      float4 v = make_float4(c[i][0], c[i][1], c[i][2], c[i][3]);
      *(float4*)&Yb[(size_t)gm * NN + n0 + tx * 4] = v;
    }
  }
}

// ---------------- BN stats: per-channel mean / rstd over (B, N) ----------------
__global__ __launch_bounds__(256)
void bn_stats(const float* __restrict__ Y, int M, float* __restrict__ mean,
              float* __restrict__ rstd) {
  int o = blockIdx.x;
  double s = 0.0, q = 0.0;
  for (int b = 0; b < NB; ++b) {
    const float* row = Y + ((size_t)b * M + o) * NPTS;
    for (int n = threadIdx.x; n < NPTS; n += 256) {
      double v = (double)row[n];
      s += v; q += v * v;
    }
  }
  for (int off = 32; off > 0; off >>= 1) {
    s += __shfl_down(s, off, 64);
    q += __shfl_down(q, off, 64);
  }
  __shared__ double ls[4], lq[4];
  int lane = threadIdx.x & 63, w = threadIdx.x >> 6;
  if (lane == 0) { ls[w] = s; lq[w] = q; }
  __syncthreads();
  if (threadIdx.x == 0) {
    double S = ls[0] + ls[1] + ls[2] + ls[3];
    double Q = lq[0] + lq[1] + lq[2] + lq[3];
    const double inv = 1.0 / (double)(NB * NPTS);
    double m = S * inv;
    double v = Q * inv - m * m;
    if (v < 0.0) v = 0.0;
    mean[o] = (float)m;
    rstd[o] = (float)(1.0 / sqrt(v + 1e-5));
  }
}

// ---------------- BN apply + ReLU ----------------
__global__ __launch_bounds__(256)
void bn_apply(const float* __restrict__ Y, float* __restrict__ A, int M,
              const float* __restrict__ g, const float* __restrict__ be,
              const float* __restrict__ mean, const float* __restrict__ rstd) {
  size_t total = (size_t)NB * M * NPTS;
  for (size_t idx = (size_t)blockIdx.x * 256 + threadIdx.x; idx < total;
       idx += (size_t)gridDim.x * 256) {
    int o = (int)((idx / NPTS) % (size_t)M);
    float v = g[o] * (Y[idx] - mean[o]) * rstd[o] + be[o];
    A[idx] = fmaxf(v, 0.f);
  }
}

// ---------------- eig path: pass 1, global max d2 per batch ----------------
__global__ __launch_bounds__(256)
void maxd2_kernel(const float* __restrict__ pc, unsigned int* __restrict__ mx) {
  int b = blockIdx.y;
  int i = blockIdx.x;
  __shared__ float sp[NPTS * 3];
  const float* pb = pc + (size_t)b * NPTS * 3;
  for (int t = threadIdx.x; t < NPTS * 3; t += 256) sp[t] = pb[t];
  __syncthreads();
  float xi = sp[i * 3], yi = sp[i * 3 + 1], zi = sp[i * 3 + 2];
  float x2i = xi * xi + yi * yi + zi * zi;
  float m = 0.f;
  for (int j = threadIdx.x; j < NPTS; j += 256) {
    if (j == i) continue;
    float xj = sp[j * 3], yj = sp[j * 3 + 1], zj = sp[j * 3 + 2];
    float x2j = xj * xj + yj * yj + zj * zj;
    float dot = xi * xj + yi * yj + zi * zj;
    float d2 = fmaxf(x2i + x2j - 2.f * dot, 0.f);
    m = fmaxf(m, d2);
  }
  for (int off = 32; off > 0; off >>= 1) m = fmaxf(m, __shfl_down(m, off, 64));
  __shared__ float lm[4];
  int lane = threadIdx.x & 63, w = threadIdx.x >> 6;
  if (lane == 0) lm[w] = m;
  __syncthreads();
  if (threadIdx.x == 0) {
    float mm = fmaxf(fmaxf(lm[0], lm[1]), fmaxf(lm[2], lm[3]));
    atomicMax(&mx[b], __float_as_uint(mm));  // nonneg floats: bit order == value order
  }
}

// ---------------- eig path: pass 2, masked covariance -> eigvals -> h3 ----------------
__global__ __launch_bounds__(256)
void eigs_kernel(const float* __restrict__ pc, const unsigned int* __restrict__ mx,
                 const float* __restrict__ ew1, const float* __restrict__ eb1,
                 const float* __restrict__ ew2, const float* __restrict__ eb2,
                 float* __restrict__ Z) {
  int b = blockIdx.y;
  int i = blockIdx.x;
  __shared__ float sp[NPTS * 3];
  const float* pb = pc + (size_t)b * NPTS * 3;
  for (int t = threadIdx.x; t < NPTS * 3; t += 256) sp[t] = pb[t];
  __syncthreads();
  float xi = sp[i * 3], yi = sp[i * 3 + 1], zi = sp[i * 3 + 2];
  float x2i = xi * xi + yi * yi + zi * zi;
  float maxd2 = fmaxf(__uint_as_float(mx[b]), 1e-12f);
  float r2 = 0.01f * maxd2;  // (RF * max_d)^2, RF = 0.1
  float cnt = 0, sx = 0, sy = 0, sz = 0;
  float sxx = 0, sxy = 0, sxz = 0, syy = 0, syz = 0, szz = 0;
  for (int j = threadIdx.x; j < NPTS; j += 256) {
    float xj = sp[j * 3], yj = sp[j * 3 + 1], zj = sp[j * 3 + 2];
    float x2j = xj * xj + yj * yj + zj * zj;
    float dot = xi * xj + yi * yj + zi * zj;
    float d2 = fmaxf(x2i + x2j - 2.f * dot, 0.f);
    d2 = fmaxf(d2, 1e-12f);
    float msk = ((d2 < r2) && (j != i)) ? 1.f : 0.f;
    cnt += msk;
    sx = fmaf(msk, xj, sx); sy = fmaf(msk, yj, sy); sz = fmaf(msk, zj, sz);
    sxx = fmaf(msk, xj * xj, sxx); sxy = fmaf(msk, xj * yj, sxy);
    sxz = fmaf(msk, xj * zj, sxz); syy = fmaf(msk, yj * yj, syy);
    syz = fmaf(msk, yj * zj, syz); szz = fmaf(msk, zj * zj, szz);
  }
  float vals[10] = {cnt, sx, sy, sz, sxx, sxy, sxz, syy, syz, szz};
  for (int off = 32; off > 0; off >>= 1)
    #pragma unroll
    for (int v = 0; v < 10; ++v) vals[v] += __shfl_down(vals[v], off, 64);
  __shared__ float red[4][10];
  int lane = threadIdx.x & 63, w = threadIdx.x >> 6;
  if (lane == 0)
    #pragma unroll
    for (int v = 0; v < 10; ++v) red[w][v] = vals[v];
  __syncthreads();
  if (threadIdx.x == 0) {
    float t[10];
    #pragma unroll
    for (int v = 0; v < 10; ++v) t[v] = red[0][v] + red[1][v] + red[2][v] + red[3][v];
    double cntd = (double)t[0];
    double denom = cntd > 1.0 ? cntd : 1.0;
    double mux = t[1] / denom, muy = t[2] / denom, muz = t[3] / denom;
    const double inv_n = 1.0 / (double)NPTS;
    double a00 = ((double)t[4] - cntd * mux * mux) * inv_n;
    double a01 = ((double)t[5] - cntd * mux * muy) * inv_n;
    double a02 = ((double)t[6] - cntd * mux * muz) * inv_n;
    double a11 = ((double)t[7] - cntd * muy * muy) * inv_n;
    double a12 = ((double)t[8] - cntd * muy * muz) * inv_n;
    double a22 = ((double)t[9] - cntd * muz * muz) * inv_n;
    // symmetric 3x3 eigvals, ascending (trig closed form)
    double e0, e1, e2;
    double p1 = a01 * a01 + a02 * a02 + a12 * a12;
    double q = (a00 + a11 + a22) / 3.0;
    double d0 = a00 - q, d1 = a11 - q, d2q = a22 - q;
    double p2 = d0 * d0 + d1 * d1 + d2q * d2q + 2.0 * p1;
    if (p2 <= 1e-30) {
      e0 = e1 = e2 = q;
    } else {
      double p = sqrt(p2 / 6.0);
      double ip = 1.0 / p;
      double b00 = d0 * ip, b11 = d1 * ip, b22 = d2q * ip;
      double b01 = a01 * ip, b02 = a02 * ip, b12 = a12 * ip;
      double detB = b00 * (b11 * b22 - b12 * b12) - b01 * (b01 * b22 - b12 * b02) +
                    b02 * (b01 * b12 - b11 * b02);
      double r = detB * 0.5;
      r = r < -1.0 ? -1.0 : (r > 1.0 ? 1.0 : r);
      double phi = acos(r) / 3.0;
      e2 = q + 2.0 * p * cos(phi);
      e0 = q + 2.0 * p * cos(phi + 2.0943951023931953);  // +2*pi/3
      e1 = 3.0 * q - e0 - e2;
    }
    float eg[3] = {(float)e0, (float)e1, (float)e2};
    float tmp[4];
    #pragma unroll
    for (int e = 0; e < 4; ++e) {
      float v = eb1[e];
      #pragma unroll
      for (int k = 0; k < 3; ++k) v = fmaf(eg[k], ew1[k * 4 + e], v);
      tmp[e] = fmaxf(v, 0.f);
    }
    #pragma unroll
    for (int f = 0; f < 4; ++f) {
      float v = eb2[f];
      #pragma unroll
      for (int e = 0; e < 4; ++e) v = fmaf(tmp[e], ew2[e * 4 + f], v);
      Z[(((size_t)b * 164) + 160 + f) * NPTS + i] = v;  // h3 transposed into Z rows 160..163
    }
  }
}

// ---------------- concat: Z rows 0..127 = h1, 128..159 = f2 ----------------
__global__ __launch_bounds__(256)
void concat_kernel(const float* __restrict__ h1, const float* __restrict__ f2,
                   float* __restrict__ Z) {
  size_t total = (size_t)NB * 160 * NPTS;
  for (size_t idx = (size_t)blockIdx.x * 256 + threadIdx.x; idx < total;
       idx += (size_t)gridDim.x * 256) {
    size_t n = idx % NPTS;
    int row = (int)((idx / NPTS) % 160);
    int b = (int)(idx / ((size_t)160 * NPTS));
    float v;
    if (row < 128) v = h1[((size_t)b * 128 + row) * NPTS + n];
    else v = f2[((size_t)b * 32 + (row - 128)) * NPTS + n];
    Z[((size_t)b * 164 + row) * NPTS + n] = v;
  }
}

extern "C" void kernel_launch(void* const* d_in, const int* in_sizes, int n_in,
                              void* d_out, int out_size, void* d_ws, size_t ws_size,
                              hipStream_t stream) {
  (void)in_sizes; (void)n_in; (void)out_size; (void)ws_size;
  const float* pc    = (const float*)d_in[0];
  const float* h1    = (const float*)d_in[1];
  const float* h2    = (const float*)d_in[2];
  const float* dgw1  = (const float*)d_in[3];
  const float* dgg1  = (const float*)d_in[5];
  const float* dgbe1 = (const float*)d_in[6];
  const float* dgw2  = (const float*)d_in[7];
  const float* dgg2  = (const float*)d_in[9];
  const float* dgbe2 = (const float*)d_in[10];
  const float* dgw3  = (const float*)d_in[11];
  const float* dgg3  = (const float*)d_in[13];
  const float* dgbe3 = (const float*)d_in[14];
  const float* ew1   = (const float*)d_in[15];
  const float* eb1   = (const float*)d_in[16];
  const float* ew2   = (const float*)d_in[17];
  const float* eb2   = (const float*)d_in[18];
  const float* w1    = (const float*)d_in[19];
  const float* g1    = (const float*)d_in[21];
  const float* be1   = (const float*)d_in[22];
  const float* w2    = (const float*)d_in[23];
  const float* g2    = (const float*)d_in[25];
  const float* be2   = (const float*)d_in[26];
  const float* w3    = (const float*)d_in[27];
  const float* g3    = (const float*)d_in[29];
  const float* be3   = (const float*)d_in[30];
  float* out = (float*)d_out;

  // workspace layout (floats)
  float* ws = (float*)d_ws;
  float* y1 = ws;                                   // 2*256*4096
  float* y2 = y1 + (size_t)2 * 256 * NPTS;          // 2*64*4096
  float* y3 = y2 + (size_t)2 * 64 * NPTS;           // 2*32*4096
  float* Z  = y3 + (size_t)2 * 32 * NPTS;           // 2*164*4096
  float* y4 = Z  + (size_t)2 * 164 * NPTS;          // 2*512*4096
  float* y5 = y4 + (size_t)2 * 512 * NPTS;          // 2*256*4096
  float* y6 = y5 + (size_t)2 * 256 * NPTS;          // 2*128*4096
  float* stats = y6 + (size_t)2 * 128 * NPTS;       // 6*1024
  unsigned int* mx = (unsigned int*)(stats + 6 * 1024);

  // eig path (independent of dg chain; writes Z rows 160..163)
  hipMemsetAsync(mx, 0, 2 * sizeof(unsigned int), stream);
  dim3 gpt(NPTS, NB);
  maxd2_kernel<<<gpt, 256, 0, stream>>>(pc, mx);
  eigs_kernel<<<gpt, 256, 0, stream>>>(pc, mx, ew1, eb1, ew2, eb2, Z);

  auto conv_bn = [&](const float* W, const float* X, float* Y, int M, int K,
                     const float* g, const float* be, float* statbuf, float* dst) {
    dim3 grid(NPTS / 64, (M + 63) / 64, NB);
    gemm_f32<<<grid, 256, 0, stream>>>(W, X, Y, M, K);
    bn_stats<<<M, 256, 0, stream>>>(Y, M, statbuf, statbuf + M);
    size_t total = (size_t)NB * M * NPTS;
    size_t want = (total + 255) / 256;
    int blocks = (int)(want < 2048 ? want : 2048);
    bn_apply<<<blocks, 256, 0, stream>>>(Y, dst, M, g, be, statbuf, statbuf + M);
  };

  // dg chain (biases skipped: BN mean-subtraction cancels them exactly)
  conv_bn(dgw1, h2, y1, 256, 1024, dgg1, dgbe1, stats + 0 * 1024, y1);
  conv_bn(dgw2, y1, y2, 64, 256, dgg2, dgbe2, stats + 1 * 1024, y2);
  conv_bn(dgw3, y2, y3, 32, 64, dgg3, dgbe3, stats + 2 * 1024, y3);

  // concat h1 + f2 into Z (h3 rows already written by eigs_kernel)
  concat_kernel<<<2048, 256, 0, stream>>>(h1, y3, Z);

  // head chain
  conv_bn(w1, Z, y4, 512, 164, g1, be1, stats + 3 * 1024, y4);
  conv_bn(w2, y4, y5, 256, 512, g2, be2, stats + 4 * 1024, y5);
  conv_bn(w3, y5, y6, 128, 256, g3, be3, stats + 5 * 1024, out + (size_t)NB * NPTS * 3);

  // output 0: xyz = pointcloud copy
  hipMemcpyAsync(d_out, d_in[0], (size_t)NB * NPTS * 3 * sizeof(float),
                 hipMemcpyDeviceToDevice, stream);
}

// Round 3
// 198.562 us; speedup vs baseline: 3.0942x; 3.0942x over previous
//
#include <hip/hip_runtime.h>
#include <math.h>

#define NPTS 4096
#define NB 2

typedef __attribute__((ext_vector_type(8))) short short8;
typedef __attribute__((ext_vector_type(4))) float f32x4;
typedef unsigned int uint32;

__device__ __forceinline__ unsigned short f2bf(float f) {
  uint32 u = __float_as_uint(f);
  uint32 r = (u + 0x7FFFu + ((u >> 16) & 1u)) >> 16;
  return (unsigned short)r;
}
__device__ __forceinline__ uint2 pack4(float a, float b, float c, float d) {
  uint2 r;
  r.x = (uint32)f2bf(a) | ((uint32)f2bf(b) << 16);
  r.y = (uint32)f2bf(c) | ((uint32)f2bf(d) << 16);
  return r;
}
__device__ __forceinline__ void gload16(const void* g, void* l) {
  __builtin_amdgcn_global_load_lds(
      (const __attribute__((address_space(1))) unsigned int*)g,
      (__attribute__((address_space(3))) unsigned int*)l, 16, 0, 0);
}

// ---------------- weight prep: f32 -> bf16, zero-pad to (Mp, Kp), NO permutation ------
struct WArgs {
  const float* src[6];
  unsigned short* dst[6];
  int M[6], K[6], Mp[6], Kp[6];
};
__global__ __launch_bounds__(256) void prep_w(WArgs a) {
  int w = blockIdx.y;
  int M = a.M[w], K = a.K[w], Mp = a.Mp[w], Kp = a.Kp[w];
  const float* src = a.src[w];
  unsigned short* dst = a.dst[w];
  int tot = Mp * Kp;
  for (int idx = blockIdx.x * 256 + threadIdx.x; idx < tot; idx += gridDim.x * 256) {
    int m = idx / Kp, k = idx % Kp;
    float v = (m < M && k < K) ? src[m * K + k] : 0.f;
    dst[idx] = f2bf(v);
  }
}

// ---------------- LDS-tiled transpose: src[b][C][4096] f32 -> dst[b][n][dstOff+c] bf16 --
__global__ __launch_bounds__(256)
void transpose_in(const float* __restrict__ src, int C, unsigned short* __restrict__ dst,
                  int dstStride, int dstOff) {
  __shared__ float tile[32][33];
  int b = blockIdx.z;
  int c0 = blockIdx.x * 32, n0 = blockIdx.y * 32;
  const float* s = src + (size_t)b * C * NPTS;
  int r = threadIdx.x >> 3, q = threadIdx.x & 7;
  float4 v = *(const float4*)(s + (size_t)(c0 + r) * NPTS + n0 + q * 4);
  tile[r][q * 4 + 0] = v.x;
  tile[r][q * 4 + 1] = v.y;
  tile[r][q * 4 + 2] = v.z;
  tile[r][q * 4 + 3] = v.w;
  __syncthreads();
  // dst[n0+r][c0 + q*4 .. +3] = tile[q*4+j][r]
  uint2 o = pack4(tile[q * 4 + 0][r], tile[q * 4 + 1][r], tile[q * 4 + 2][r],
                  tile[q * 4 + 3][r]);
  *(uint2*)(dst + ((size_t)b * NPTS + n0 + r) * dstStride + dstOff + c0 + q * 4) = o;
}

// ---------------- zero Zt cols 164..191 ----------------
__global__ __launch_bounds__(256) void zero_z(unsigned short* __restrict__ Zt) {
  int tot = NB * NPTS * 7;
  for (int idx = blockIdx.x * 256 + threadIdx.x; idx < tot; idx += gridDim.x * 256) {
    int u = idx % 7;
    int n = (idx / 7) % NPTS;
    int b = idx / (7 * NPTS);
    *(uint2*)(Zt + ((size_t)b * NPTS + n) * 192 + 164 + u * 4) = make_uint2(0u, 0u);
  }
}

// ---------------- MFMA GEMM (transposed activations):
// Yt[b][n][m] = sum_k Wp[m][k] * Xt[b][n][k]
// block tile 64(M) x 128(N), BK=64, 4 waves (2m x 2n), per-wave 32m x 64n
// LDS: Xt tile [128 n][64 k] bf16, row stride 144B (padded), double-buffered.
// A-frag: lane reads Wp[m][8 contiguous k]; B-frag: ds_read_b128 of Xt row (8 contig k).
// Verified layout (m92/m97): lane&15 = m/n, lane>>4 = k-octet, 8 contiguous k/lane.
__global__ __launch_bounds__(256)
void gemm_mfma(const unsigned short* __restrict__ Wp, const unsigned short* __restrict__ Xt,
               float* __restrict__ Yt, float* __restrict__ psum, float* __restrict__ psq,
               int M, int Mp, int Kp) {
  __shared__ char smem[2][18432];  // 128 rows x 144B, x2
  const int b = blockIdx.z, nblk = blockIdx.x, mt = blockIdx.y;
  const int n0 = nblk * 128, m0 = mt * 64;
  const int tid = threadIdx.x, lane = tid & 63, wid = tid >> 6;
  const int wm = wid >> 1, wn = wid & 1;
  const int g = lane >> 4, c = lane & 15;
  const unsigned short* Xb = Xt + (size_t)b * NPTS * Kp;
  const int ktiles = Kp >> 6;

  auto stage = [&](int buf, int t) {
    int k0 = t << 6;
#pragma unroll
    for (int i = 0; i < 5; ++i) {
      int u = tid + i * 256;
      if (u < 1152) {                 // wave-uniform branch
        int n = u / 9, r9 = u % 9;
        int k = r9 < 8 ? r9 * 8 : 0;  // slot 8 = 16B row pad (never read)
        gload16(Xb + (size_t)(n0 + n) * Kp + k0 + k, &smem[buf][u * 16]);
      }
    }
  };
  auto loadA = [&](int t, uint4* A) {
    const unsigned short* base = Wp + (size_t)(m0 + wm * 32 + c) * Kp + (t << 6) + g * 8;
#pragma unroll
    for (int mf = 0; mf < 2; ++mf)
#pragma unroll
      for (int kw = 0; kw < 2; ++kw)
        A[mf * 2 + kw] = *(const uint4*)(base + (size_t)mf * 16 * Kp + kw * 32);
  };

  f32x4 acc[2][4] = {};
  uint4 Acur[4], Anext[4];
  stage(0, 0);
  loadA(0, Acur);
  __syncthreads();
  int cur = 0;

  for (int t = 0; t < ktiles; ++t) {
    if (t + 1 < ktiles) {
      loadA(t + 1, Anext);
      stage(cur ^ 1, t + 1);
    }
#pragma unroll
    for (int kw = 0; kw < 2; ++kw) {
      union { uint4 u; short8 s; } a0, a1;
      a0.u = Acur[0 * 2 + kw];
      a1.u = Acur[1 * 2 + kw];
#pragma unroll
      for (int nf = 0; nf < 4; ++nf) {
        union { uint4 u; short8 s; } bf;
        bf.u = *(const uint4*)&smem[cur][(wn * 64 + nf * 16 + c) * 144 + kw * 64 + g * 16];
        acc[0][nf] = __builtin_amdgcn_mfma_f32_16x16x32_bf16(a0.s, bf.s, acc[0][nf], 0, 0, 0);
        acc[1][nf] = __builtin_amdgcn_mfma_f32_16x16x32_bf16(a1.s, bf.s, acc[1][nf], 0, 0, 0);
      }
    }
    __syncthreads();
    cur ^= 1;
#pragma unroll
    for (int i = 0; i < 4; ++i) Acur[i] = Anext[i];
  }

  // C-write: D row m = m0+wm*32+mf*16+g*4+r, col n = n0+wn*64+nf*16+c  ->  Yt[n][m]
#pragma unroll
  for (int nf = 0; nf < 4; ++nf) {
    int n = n0 + wn * 64 + nf * 16 + c;
    float* yrow = Yt + ((size_t)b * NPTS + n) * Mp;
#pragma unroll
    for (int mf = 0; mf < 2; ++mf) {
      int mbase = m0 + wm * 32 + mf * 16 + g * 4;
      float4 v = make_float4(acc[mf][nf][0], acc[mf][nf][1], acc[mf][nf][2], acc[mf][nf][3]);
      *(float4*)(yrow + mbase) = v;
    }
  }
  // BN partials: per channel, sum over this wave's 64 n; slot per (b, nblk, wn)
  int slot = (b * 32 + nblk) * 2 + wn;
#pragma unroll
  for (int mf = 0; mf < 2; ++mf)
#pragma unroll
    for (int r = 0; r < 4; ++r) {
      float s = 0.f, q = 0.f;
#pragma unroll
      for (int nf = 0; nf < 4; ++nf) {
        float v = acc[mf][nf][r];
        s += v;
        q += v * v;
      }
#pragma unroll
      for (int m = 1; m < 16; m <<= 1) {
        s += __shfl_xor(s, m, 64);
        q += __shfl_xor(q, m, 64);
      }
      int row = m0 + wm * 32 + mf * 16 + g * 4 + r;
      if (c == 0 && row < M) {
        psum[(size_t)row * 128 + slot] = s;
        psq[(size_t)row * 128 + slot] = q;
      }
    }
}

// ---------------- BN finalize: 128 slots -> a_[ch], b_[ch] ----------------
__global__ __launch_bounds__(128)
void bn_finalize(const float* __restrict__ psum, const float* __restrict__ psq,
                 const float* __restrict__ gamma, const float* __restrict__ beta,
                 float* __restrict__ a_, float* __restrict__ b_) {
  int ch = blockIdx.x, t = threadIdx.x;
  float s = psum[(size_t)ch * 128 + t];
  float q = psq[(size_t)ch * 128 + t];
#pragma unroll
  for (int m = 1; m < 64; m <<= 1) {
    s += __shfl_xor(s, m, 64);
    q += __shfl_xor(q, m, 64);
  }
  __shared__ float ws[2][2];
  if ((t & 63) == 0) { ws[t >> 6][0] = s; ws[t >> 6][1] = q; }
  __syncthreads();
  if (t == 0) {
    float S = ws[0][0] + ws[1][0];
    float Q = ws[0][1] + ws[1][1];
    const float inv = 1.f / (float)(NB * NPTS);
    float mean = S * inv;
    float var = Q * inv - mean * mean;
    if (var < 0.f) var = 0.f;
    float aa = rsqrtf(var + 1e-5f) * gamma[ch];
    a_[ch] = aa;
    b_[ch] = beta[ch] - mean * aa;
  }
}

// ---------------- BN apply + ReLU, Xt layout -> bf16 dst (Xt layout) ----------------
__global__ __launch_bounds__(256)
void bn_apply_t(const float* __restrict__ Yt, const float* __restrict__ a_,
                const float* __restrict__ b_, unsigned short* __restrict__ dst,
                int Mp, int Mv4, int dstStride, int dstOff) {
  int tot = NB * NPTS * Mv4;
  for (int idx = blockIdx.x * 256 + threadIdx.x; idx < tot; idx += gridDim.x * 256) {
    int c4 = idx % Mv4;
    int n = (idx / Mv4) & (NPTS - 1);
    int b = idx / (Mv4 * NPTS);
    float4 v = *(const float4*)(Yt + ((size_t)b * NPTS + n) * Mp + c4 * 4);
    float4 aa = ((const float4*)a_)[c4];
    float4 bb = ((const float4*)b_)[c4];
    uint2 o = pack4(fmaxf(v.x * aa.x + bb.x, 0.f), fmaxf(v.y * aa.y + bb.y, 0.f),
                    fmaxf(v.z * aa.z + bb.z, 0.f), fmaxf(v.w * aa.w + bb.w, 0.f));
    *(uint2*)(dst + ((size_t)b * NPTS + n) * dstStride + dstOff + c4 * 4) = o;
  }
}

// ---------------- final: BN apply + ReLU + transpose -> z[b][128][4096] f32 ----------
__global__ __launch_bounds__(256)
void bn_out_t(const float* __restrict__ Yt, const float* __restrict__ a_,
              const float* __restrict__ b_, float* __restrict__ z) {
  __shared__ float tile[32][33];
  int b = blockIdx.z;
  int c0 = blockIdx.x * 32, n0 = blockIdx.y * 32;
  int r = threadIdx.x >> 3, q = threadIdx.x & 7;
  float4 v = *(const float4*)(Yt + ((size_t)b * NPTS + n0 + r) * 128 + c0 + q * 4);
  float4 aa = *(const float4*)(a_ + c0 + q * 4);
  float4 bb = *(const float4*)(b_ + c0 + q * 4);
  tile[r][q * 4 + 0] = fmaxf(v.x * aa.x + bb.x, 0.f);
  tile[r][q * 4 + 1] = fmaxf(v.y * aa.y + bb.y, 0.f);
  tile[r][q * 4 + 2] = fmaxf(v.z * aa.z + bb.z, 0.f);
  tile[r][q * 4 + 3] = fmaxf(v.w * aa.w + bb.w, 0.f);
  __syncthreads();
  // z[c0+r][n0 + q*4 + j] = tile[q*4+j][r]
  float4 o = make_float4(tile[q * 4 + 0][r], tile[q * 4 + 1][r], tile[q * 4 + 2][r],
                         tile[q * 4 + 3][r]);
  *(float4*)(z + ((size_t)b * 128 + c0 + r) * NPTS + n0 + q * 4) = o;
}

// ---------------- eig pass 1: per-batch global max d2 (32 i per block) ----------------
__global__ __launch_bounds__(256)
void maxd2_kernel(const float* __restrict__ pc, unsigned int* __restrict__ mx) {
  __shared__ float sp[NPTS * 3];
  __shared__ float red[4][32];
  int b = blockIdx.y;
  const float* pb = pc + (size_t)b * NPTS * 3;
  for (int t = threadIdx.x; t < NPTS * 3; t += 256) sp[t] = pb[t];
  __syncthreads();
  int il = threadIdx.x & 31, sl = threadIdx.x >> 5;
  int i = blockIdx.x * 32 + il;
  float xi = sp[i * 3], yi = sp[i * 3 + 1], zi = sp[i * 3 + 2];
  float x2i = xi * xi + yi * yi + zi * zi;
  float m = 0.f;
#pragma unroll 4
  for (int j = sl * 512, e = sl * 512 + 512; j < e; ++j) {
    float xj = sp[j * 3], yj = sp[j * 3 + 1], zj = sp[j * 3 + 2];
    float x2j = xj * xj + yj * yj + zj * zj;
    float dot = xi * xj + yi * yj + zi * zj;
    float d2 = fmaxf(x2i + x2j - 2.f * dot, 0.f);  // d2(i,i)==0 exactly
    m = fmaxf(m, d2);
  }
  m = fmaxf(m, __shfl_xor(m, 32, 64));
  int w = threadIdx.x >> 6;
  if ((threadIdx.x & 63) < 32) red[w][il] = m;
  __syncthreads();
  if (threadIdx.x < 32) {
    float v = fmaxf(fmaxf(red[0][threadIdx.x], red[1][threadIdx.x]),
                    fmaxf(red[2][threadIdx.x], red[3][threadIdx.x]));
#pragma unroll
    for (int off = 16; off > 0; off >>= 1) v = fmaxf(v, __shfl_down(v, off, 64));
    if (threadIdx.x == 0) atomicMax(&mx[b], __float_as_uint(v));
  }
}

// ---------------- eig pass 2: masked cov -> eigvals -> tiny MLP -> Zt cols 160..163 ---
__global__ __launch_bounds__(256)
void eigs_kernel(const float* __restrict__ pc, const unsigned int* __restrict__ mx,
                 const float* __restrict__ ew1, const float* __restrict__ eb1,
                 const float* __restrict__ ew2, const float* __restrict__ eb2,
                 unsigned short* __restrict__ Zt) {
  __shared__ float sp[NPTS * 3];
  __shared__ float red[4][32][10];
  int b = blockIdx.y;
  const float* pb = pc + (size_t)b * NPTS * 3;
  for (int t = threadIdx.x; t < NPTS * 3; t += 256) sp[t] = pb[t];
  __syncthreads();
  int il = threadIdx.x & 31, sl = threadIdx.x >> 5;
  int i = blockIdx.x * 32 + il;
  float xi = sp[i * 3], yi = sp[i * 3 + 1], zi = sp[i * 3 + 2];
  float x2i = xi * xi + yi * yi + zi * zi;
  float maxd2 = fmaxf(__uint_as_float(mx[b]), 1e-12f);
  float r2 = 0.01f * maxd2;
  float vals[10];
#pragma unroll
  for (int v = 0; v < 10; ++v) vals[v] = 0.f;
#pragma unroll 2
  for (int j = sl * 512, e = sl * 512 + 512; j < e; ++j) {
    float xj = sp[j * 3], yj = sp[j * 3 + 1], zj = sp[j * 3 + 2];
    float x2j = xj * xj + yj * yj + zj * zj;
    float dot = xi * xj + yi * yj + zi * zj;
    float d2 = fmaxf(x2i + x2j - 2.f * dot, 0.f);
    d2 = fmaxf(d2, 1e-12f);
    float msk = ((d2 < r2) && (j != i)) ? 1.f : 0.f;
    vals[0] += msk;
    vals[1] = fmaf(msk, xj, vals[1]);
    vals[2] = fmaf(msk, yj, vals[2]);
    vals[3] = fmaf(msk, zj, vals[3]);
    vals[4] = fmaf(msk, xj * xj, vals[4]);
    vals[5] = fmaf(msk, xj * yj, vals[5]);
    vals[6] = fmaf(msk, xj * zj, vals[6]);
    vals[7] = fmaf(msk, yj * yj, vals[7]);
    vals[8] = fmaf(msk, yj * zj, vals[8]);
    vals[9] = fmaf(msk, zj * zj, vals[9]);
  }
#pragma unroll
  for (int v = 0; v < 10; ++v) vals[v] += __shfl_xor(vals[v], 32, 64);
  int w = threadIdx.x >> 6;
  if ((threadIdx.x & 63) < 32)
#pragma unroll
    for (int v = 0; v < 10; ++v) red[w][il][v] = vals[v];
  __syncthreads();
  if (threadIdx.x < 32) {
    int ii = blockIdx.x * 32 + threadIdx.x;
    float t[10];
#pragma unroll
    for (int v = 0; v < 10; ++v)
      t[v] = red[0][threadIdx.x][v] + red[1][threadIdx.x][v] + red[2][threadIdx.x][v] +
             red[3][threadIdx.x][v];
    double cntd = (double)t[0];
    double denom = cntd > 1.0 ? cntd : 1.0;
    double mux = t[1] / denom, muy = t[2] / denom, muz = t[3] / denom;
    const double inv_n = 1.0 / (double)NPTS;
    double a00 = ((double)t[4] - cntd * mux * mux) * inv_n;
    double a01 = ((double)t[5] - cntd * mux * muy) * inv_n;
    double a02 = ((double)t[6] - cntd * mux * muz) * inv_n;
    double a11 = ((double)t[7] - cntd * muy * muy) * inv_n;
    double a12 = ((double)t[8] - cntd * muy * muz) * inv_n;
    double a22 = ((double)t[9] - cntd * muz * muz) * inv_n;
    double e0, e1, e2;
    double p1 = a01 * a01 + a02 * a02 + a12 * a12;
    double q = (a00 + a11 + a22) / 3.0;
    double d0 = a00 - q, d1 = a11 - q, d2q = a22 - q;
    double p2 = d0 * d0 + d1 * d1 + d2q * d2q + 2.0 * p1;
    if (p2 <= 1e-30) {
      e0 = e1 = e2 = q;
    } else {
      double p = sqrt(p2 / 6.0);
      double ip = 1.0 / p;
      double b00 = d0 * ip, b11 = d1 * ip, b22 = d2q * ip;
      double b01 = a01 * ip, b02 = a02 * ip, b12 = a12 * ip;
      double detB = b00 * (b11 * b22 - b12 * b12) - b01 * (b01 * b22 - b12 * b02) +
                    b02 * (b01 * b12 - b11 * b02);
      double r = detB * 0.5;
      r = r < -1.0 ? -1.0 : (r > 1.0 ? 1.0 : r);
      double phi = acos(r) / 3.0;
      e2 = q + 2.0 * p * cos(phi);
      e0 = q + 2.0 * p * cos(phi + 2.0943951023931953);
      e1 = 3.0 * q - e0 - e2;
    }
    float eg[3] = {(float)e0, (float)e1, (float)e2};
    float tmp[4];
#pragma unroll
    for (int e = 0; e < 4; ++e) {
      float v = eb1[e];
#pragma unroll
      for (int k = 0; k < 3; ++k) v = fmaf(eg[k], ew1[k * 4 + e], v);
      tmp[e] = fmaxf(v, 0.f);
    }
    float h3[4];
#pragma unroll
    for (int f = 0; f < 4; ++f) {
      float v = eb2[f];
#pragma unroll
      for (int e = 0; e < 4; ++e) v = fmaf(tmp[e], ew2[e * 4 + f], v);
      h3[f] = v;
    }
    *(uint2*)(Zt + ((size_t)b * NPTS + ii) * 192 + 160) = pack4(h3[0], h3[1], h3[2], h3[3]);
  }
}

extern "C" void kernel_launch(void* const* d_in, const int* in_sizes, int n_in,
                              void* d_out, int out_size, void* d_ws, size_t ws_size,
                              hipStream_t stream) {
  (void)in_sizes; (void)n_in; (void)out_size; (void)ws_size;
  const float* pc    = (const float*)d_in[0];
  const float* h1    = (const float*)d_in[1];
  const float* h2    = (const float*)d_in[2];
  const float* dgw1  = (const float*)d_in[3];
  const float* dgg1  = (const float*)d_in[5];
  const float* dgbe1 = (const float*)d_in[6];
  const float* dgw2  = (const float*)d_in[7];
  const float* dgg2  = (const float*)d_in[9];
  const float* dgbe2 = (const float*)d_in[10];
  const float* dgw3  = (const float*)d_in[11];
  const float* dgg3  = (const float*)d_in[13];
  const float* dgbe3 = (const float*)d_in[14];
  const float* ew1   = (const float*)d_in[15];
  const float* eb1   = (const float*)d_in[16];
  const float* ew2   = (const float*)d_in[17];
  const float* eb2   = (const float*)d_in[18];
  const float* w1    = (const float*)d_in[19];
  const float* g1    = (const float*)d_in[21];
  const float* be1   = (const float*)d_in[22];
  const float* w2    = (const float*)d_in[23];
  const float* g2    = (const float*)d_in[25];
  const float* be2   = (const float*)d_in[26];
  const float* w3    = (const float*)d_in[27];
  const float* g3    = (const float*)d_in[29];
  const float* be3   = (const float*)d_in[30];
  float* out = (float*)d_out;

  // ---- workspace layout ----
  char* p = (char*)d_ws;
  auto take = [&](size_t bytes) { char* r = p; p += (bytes + 255) & ~(size_t)255; return r; };
  unsigned short* h2t = (unsigned short*)take((size_t)NB * NPTS * 1024 * 2);
  unsigned short* y1t = (unsigned short*)take((size_t)NB * NPTS * 256 * 2);
  unsigned short* y2t = (unsigned short*)take((size_t)NB * NPTS * 64 * 2);
  unsigned short* Zt  = (unsigned short*)take((size_t)NB * NPTS * 192 * 2);
  unsigned short* y4t = (unsigned short*)take((size_t)NB * NPTS * 512 * 2);
  unsigned short* y5t = (unsigned short*)take((size_t)NB * NPTS * 256 * 2);
  unsigned short* wp1 = (unsigned short*)take((size_t)256 * 1024 * 2);
  unsigned short* wp2 = (unsigned short*)take((size_t)64 * 256 * 2);
  unsigned short* wp3 = (unsigned short*)take((size_t)64 * 64 * 2);
  unsigned short* wp4 = (unsigned short*)take((size_t)512 * 192 * 2);
  unsigned short* wp5 = (unsigned short*)take((size_t)256 * 512 * 2);
  unsigned short* wp6 = (unsigned short*)take((size_t)128 * 256 * 2);
  float* Yf   = (float*)take((size_t)NB * NPTS * 512 * 4);
  float* psum = (float*)take((size_t)512 * 128 * 4);
  float* psq  = (float*)take((size_t)512 * 128 * 4);
  float* a_   = (float*)take((size_t)512 * 4);
  float* b_   = (float*)take((size_t)512 * 4);
  unsigned int* mx = (unsigned int*)take(256);

  // ---- weight prep (no permutation; rows/cols beyond M/K zero) ----
  WArgs wa;
  wa.src[0] = dgw1; wa.dst[0] = wp1; wa.M[0] = 256; wa.K[0] = 1024; wa.Mp[0] = 256; wa.Kp[0] = 1024;
  wa.src[1] = dgw2; wa.dst[1] = wp2; wa.M[1] = 64;  wa.K[1] = 256;  wa.Mp[1] = 64;  wa.Kp[1] = 256;
  wa.src[2] = dgw3; wa.dst[2] = wp3; wa.M[2] = 32;  wa.K[2] = 64;   wa.Mp[2] = 64;  wa.Kp[2] = 64;
  wa.src[3] = w1;   wa.dst[3] = wp4; wa.M[3] = 512; wa.K[3] = 164;  wa.Mp[3] = 512; wa.Kp[3] = 192;
  wa.src[4] = w2;   wa.dst[4] = wp5; wa.M[4] = 256; wa.K[4] = 512;  wa.Mp[4] = 256; wa.Kp[4] = 512;
  wa.src[5] = w3;   wa.dst[5] = wp6; wa.M[5] = 128; wa.K[5] = 256;  wa.Mp[5] = 128; wa.Kp[5] = 256;
  prep_w<<<dim3(256, 6), 256, 0, stream>>>(wa);

  // ---- input transposes: h2 -> h2t[b][n][1024]; h1 -> Zt cols 0..127; pad cols ----
  transpose_in<<<dim3(32, 128, NB), 256, 0, stream>>>(h2, 1024, h2t, 1024, 0);
  transpose_in<<<dim3(4, 128, NB), 256, 0, stream>>>(h1, 128, Zt, 192, 0);
  zero_z<<<224, 256, 0, stream>>>(Zt);

  // ---- eig path (writes Zt cols 160..163) ----
  hipMemsetAsync(mx, 0, 2 * sizeof(unsigned int), stream);
  dim3 egrid(NPTS / 32, NB);
  maxd2_kernel<<<egrid, 256, 0, stream>>>(pc, mx);
  eigs_kernel<<<egrid, 256, 0, stream>>>(pc, mx, ew1, eb1, ew2, eb2, Zt);

  auto layer = [&](const unsigned short* Wp, const unsigned short* X, int M, int Mp, int Kp,
                   const float* g, const float* be, unsigned short* dst, int dstStride,
                   int dstOff, int Mvalid) {
    dim3 grid(NPTS / 128, Mp / 64, NB);
    gemm_mfma<<<grid, 256, 0, stream>>>(Wp, X, Yf, psum, psq, M, Mp, Kp);
    bn_finalize<<<M, 128, 0, stream>>>(psum, psq, g, be, a_, b_);
    int tot = NB * NPTS * (Mvalid / 4);
    int blocks = (tot + 255) / 256;
    if (blocks > 2048) blocks = 2048;
    bn_apply_t<<<blocks, 256, 0, stream>>>(Yf, a_, b_, dst, Mp, Mvalid / 4, dstStride, dstOff);
  };

  // dg chain (conv biases cancel under BN mean subtraction)
  layer(wp1, h2t, 256, 256, 1024, dgg1, dgbe1, y1t, 256, 0, 256);
  layer(wp2, y1t, 64, 64, 256, dgg2, dgbe2, y2t, 64, 0, 64);
  layer(wp3, y2t, 32, 64, 64, dgg3, dgbe3, Zt, 192, 128, 32);  // f2 -> Zt cols 128..159

  // head chain
  layer(wp4, Zt, 512, 512, 192, g1, be1, y4t, 512, 0, 512);
  layer(wp5, y4t, 256, 256, 512, g2, be2, y5t, 256, 0, 256);
  {
    dim3 grid(NPTS / 128, 2, NB);
    gemm_mfma<<<grid, 256, 0, stream>>>(wp6, y5t, Yf, psum, psq, 128, 128, 256);
    bn_finalize<<<128, 128, 0, stream>>>(psum, psq, g3, be3, a_, b_);
    bn_out_t<<<dim3(4, 128, NB), 256, 0, stream>>>(Yf, a_, b_, out + (size_t)NB * NPTS * 3);
  }

  // output 0: xyz copy
  hipMemcpyAsync(d_out, d_in[0], (size_t)NB * NPTS * 3 * sizeof(float),
                 hipMemcpyDeviceToDevice, stream);
}

// Round 4
// 188.113 us; speedup vs baseline: 3.2661x; 1.0555x over previous
//
#include <hip/hip_runtime.h>
#include <math.h>

#define NPTS 4096
#define NB 2

typedef __attribute__((ext_vector_type(8))) short short8;
typedef __attribute__((ext_vector_type(4))) float f32x4;
typedef unsigned int uint32;

__device__ __forceinline__ unsigned short f2bf(float f) {
  uint32 u = __float_as_uint(f);
  uint32 r = (u + 0x7FFFu + ((u >> 16) & 1u)) >> 16;
  return (unsigned short)r;
}
__device__ __forceinline__ uint2 pack4(float a, float b, float c, float d) {
  uint2 r;
  r.x = (uint32)f2bf(a) | ((uint32)f2bf(b) << 16);
  r.y = (uint32)f2bf(c) | ((uint32)f2bf(d) << 16);
  return r;
}
__device__ __forceinline__ void gload16(const void* g, void* l) {
  __builtin_amdgcn_global_load_lds(
      (const __attribute__((address_space(1))) unsigned int*)g,
      (__attribute__((address_space(3))) unsigned int*)l, 16, 0, 0);
}

// ---------------- weight prep: f32 -> bf16, zero-pad to (Mp, Kp) ----------------
struct WArgs {
  const float* src[6];
  unsigned short* dst[6];
  int M[6], K[6], Mp[6], Kp[6];
};
__global__ __launch_bounds__(256) void prep_w(WArgs a) {
  int w = blockIdx.y;
  int M = a.M[w], K = a.K[w], Mp = a.Mp[w], Kp = a.Kp[w];
  const float* src = a.src[w];
  unsigned short* dst = a.dst[w];
  int tot = Mp * Kp;
  for (int idx = blockIdx.x * 256 + threadIdx.x; idx < tot; idx += gridDim.x * 256) {
    int m = idx / Kp, k = idx % Kp;
    float v = (m < M && k < K) ? src[m * K + k] : 0.f;
    dst[idx] = f2bf(v);
  }
}

// ---------------- LDS-tiled transpose: src[b][C][4096] f32 -> dst[b][n][dstOff+c] bf16 --
__global__ __launch_bounds__(256)
void transpose_in(const float* __restrict__ src, int C, unsigned short* __restrict__ dst,
                  int dstStride, int dstOff) {
  __shared__ float tile[32][33];
  int b = blockIdx.z;
  int c0 = blockIdx.x * 32, n0 = blockIdx.y * 32;
  const float* s = src + (size_t)b * C * NPTS;
  int r = threadIdx.x >> 3, q = threadIdx.x & 7;
  float4 v = *(const float4*)(s + (size_t)(c0 + r) * NPTS + n0 + q * 4);
  tile[r][q * 4 + 0] = v.x;
  tile[r][q * 4 + 1] = v.y;
  tile[r][q * 4 + 2] = v.z;
  tile[r][q * 4 + 3] = v.w;
  __syncthreads();
  uint2 o = pack4(tile[q * 4 + 0][r], tile[q * 4 + 1][r], tile[q * 4 + 2][r],
                  tile[q * 4 + 3][r]);
  *(uint2*)(dst + ((size_t)b * NPTS + n0 + r) * dstStride + dstOff + c0 + q * 4) = o;
}

// ---------------- zero Zt cols 164..191 ----------------
__global__ __launch_bounds__(256) void zero_z(unsigned short* __restrict__ Zt) {
  int tot = NB * NPTS * 7;
  for (int idx = blockIdx.x * 256 + threadIdx.x; idx < tot; idx += gridDim.x * 256) {
    int u = idx % 7;
    int n = (idx / 7) % NPTS;
    int b = idx / (7 * NPTS);
    *(uint2*)(Zt + ((size_t)b * NPTS + n) * 192 + 164 + u * 4) = make_uint2(0u, 0u);
  }
}

// ---------------- MFMA GEMM (transposed activations) — unchanged from round 3 -------
__global__ __launch_bounds__(256)
void gemm_mfma(const unsigned short* __restrict__ Wp, const unsigned short* __restrict__ Xt,
               float* __restrict__ Yt, float* __restrict__ psum, float* __restrict__ psq,
               int M, int Mp, int Kp) {
  __shared__ char smem[2][18432];  // 128 rows x 144B, x2
  const int b = blockIdx.z, nblk = blockIdx.x, mt = blockIdx.y;
  const int n0 = nblk * 128, m0 = mt * 64;
  const int tid = threadIdx.x, lane = tid & 63, wid = tid >> 6;
  const int wm = wid >> 1, wn = wid & 1;
  const int g = lane >> 4, c = lane & 15;
  const unsigned short* Xb = Xt + (size_t)b * NPTS * Kp;
  const int ktiles = Kp >> 6;

  auto stage = [&](int buf, int t) {
    int k0 = t << 6;
#pragma unroll
    for (int i = 0; i < 5; ++i) {
      int u = tid + i * 256;
      if (u < 1152) {
        int n = u / 9, r9 = u % 9;
        int k = r9 < 8 ? r9 * 8 : 0;  // slot 8 = 16B row pad (never read)
        gload16(Xb + (size_t)(n0 + n) * Kp + k0 + k, &smem[buf][u * 16]);
      }
    }
  };
  auto loadA = [&](int t, uint4* A) {
    const unsigned short* base = Wp + (size_t)(m0 + wm * 32 + c) * Kp + (t << 6) + g * 8;
#pragma unroll
    for (int mf = 0; mf < 2; ++mf)
#pragma unroll
      for (int kw = 0; kw < 2; ++kw)
        A[mf * 2 + kw] = *(const uint4*)(base + (size_t)mf * 16 * Kp + kw * 32);
  };

  f32x4 acc[2][4] = {};
  uint4 Acur[4], Anext[4];
  stage(0, 0);
  loadA(0, Acur);
  __syncthreads();
  int cur = 0;

  for (int t = 0; t < ktiles; ++t) {
    if (t + 1 < ktiles) {
      loadA(t + 1, Anext);
      stage(cur ^ 1, t + 1);
    }
#pragma unroll
    for (int kw = 0; kw < 2; ++kw) {
      union { uint4 u; short8 s; } a0, a1;
      a0.u = Acur[0 * 2 + kw];
      a1.u = Acur[1 * 2 + kw];
#pragma unroll
      for (int nf = 0; nf < 4; ++nf) {
        union { uint4 u; short8 s; } bf;
        bf.u = *(const uint4*)&smem[cur][(wn * 64 + nf * 16 + c) * 144 + kw * 64 + g * 16];
        acc[0][nf] = __builtin_amdgcn_mfma_f32_16x16x32_bf16(a0.s, bf.s, acc[0][nf], 0, 0, 0);
        acc[1][nf] = __builtin_amdgcn_mfma_f32_16x16x32_bf16(a1.s, bf.s, acc[1][nf], 0, 0, 0);
      }
    }
    __syncthreads();
    cur ^= 1;
#pragma unroll
    for (int i = 0; i < 4; ++i) Acur[i] = Anext[i];
  }

#pragma unroll
  for (int nf = 0; nf < 4; ++nf) {
    int n = n0 + wn * 64 + nf * 16 + c;
    float* yrow = Yt + ((size_t)b * NPTS + n) * Mp;
#pragma unroll
    for (int mf = 0; mf < 2; ++mf) {
      int mbase = m0 + wm * 32 + mf * 16 + g * 4;
      float4 v = make_float4(acc[mf][nf][0], acc[mf][nf][1], acc[mf][nf][2], acc[mf][nf][3]);
      *(float4*)(yrow + mbase) = v;
    }
  }
  int slot = (b * 32 + nblk) * 2 + wn;
#pragma unroll
  for (int mf = 0; mf < 2; ++mf)
#pragma unroll
    for (int r = 0; r < 4; ++r) {
      float s = 0.f, q = 0.f;
#pragma unroll
      for (int nf = 0; nf < 4; ++nf) {
        float v = acc[mf][nf][r];
        s += v;
        q += v * v;
      }
#pragma unroll
      for (int m = 1; m < 16; m <<= 1) {
        s += __shfl_xor(s, m, 64);
        q += __shfl_xor(q, m, 64);
      }
      int row = m0 + wm * 32 + mf * 16 + g * 4 + r;
      if (c == 0 && row < M) {
        psum[(size_t)row * 128 + slot] = s;
        psq[(size_t)row * 128 + slot] = q;
      }
    }
}

// ---------------- BN finalize: 128 slots -> a_[ch], b_[ch] ----------------
__global__ __launch_bounds__(128)
void bn_finalize(const float* __restrict__ psum, const float* __restrict__ psq,
                 const float* __restrict__ gamma, const float* __restrict__ beta,
                 float* __restrict__ a_, float* __restrict__ b_) {
  int ch = blockIdx.x, t = threadIdx.x;
  float s = psum[(size_t)ch * 128 + t];
  float q = psq[(size_t)ch * 128 + t];
#pragma unroll
  for (int m = 1; m < 64; m <<= 1) {
    s += __shfl_xor(s, m, 64);
    q += __shfl_xor(q, m, 64);
  }
  __shared__ float ws[2][2];
  if ((t & 63) == 0) { ws[t >> 6][0] = s; ws[t >> 6][1] = q; }
  __syncthreads();
  if (t == 0) {
    float S = ws[0][0] + ws[1][0];
    float Q = ws[0][1] + ws[1][1];
    const float inv = 1.f / (float)(NB * NPTS);
    float mean = S * inv;
    float var = Q * inv - mean * mean;
    if (var < 0.f) var = 0.f;
    float aa = rsqrtf(var + 1e-5f) * gamma[ch];
    a_[ch] = aa;
    b_[ch] = beta[ch] - mean * aa;
  }
}

// ---------------- BN apply + ReLU, Xt layout -> bf16 dst (Xt layout) ----------------
__global__ __launch_bounds__(256)
void bn_apply_t(const float* __restrict__ Yt, const float* __restrict__ a_,
                const float* __restrict__ b_, unsigned short* __restrict__ dst,
                int Mp, int Mv4, int dstStride, int dstOff) {
  int tot = NB * NPTS * Mv4;
  for (int idx = blockIdx.x * 256 + threadIdx.x; idx < tot; idx += gridDim.x * 256) {
    int c4 = idx % Mv4;
    int n = (idx / Mv4) & (NPTS - 1);
    int b = idx / (Mv4 * NPTS);
    float4 v = *(const float4*)(Yt + ((size_t)b * NPTS + n) * Mp + c4 * 4);
    float4 aa = ((const float4*)a_)[c4];
    float4 bb = ((const float4*)b_)[c4];
    uint2 o = pack4(fmaxf(v.x * aa.x + bb.x, 0.f), fmaxf(v.y * aa.y + bb.y, 0.f),
                    fmaxf(v.z * aa.z + bb.z, 0.f), fmaxf(v.w * aa.w + bb.w, 0.f));
    *(uint2*)(dst + ((size_t)b * NPTS + n) * dstStride + dstOff + c4 * 4) = o;
  }
}

// ---------------- final: BN apply + ReLU + transpose -> z[b][128][4096] f32 ----------
__global__ __launch_bounds__(256)
void bn_out_t(const float* __restrict__ Yt, const float* __restrict__ a_,
              const float* __restrict__ b_, float* __restrict__ z) {
  __shared__ float tile[32][33];
  int b = blockIdx.z;
  int c0 = blockIdx.x * 32, n0 = blockIdx.y * 32;
  int r = threadIdx.x >> 3, q = threadIdx.x & 7;
  float4 v = *(const float4*)(Yt + ((size_t)b * NPTS + n0 + r) * 128 + c0 + q * 4);
  float4 aa = *(const float4*)(a_ + c0 + q * 4);
  float4 bb = *(const float4*)(b_ + c0 + q * 4);
  tile[r][q * 4 + 0] = fmaxf(v.x * aa.x + bb.x, 0.f);
  tile[r][q * 4 + 1] = fmaxf(v.y * aa.y + bb.y, 0.f);
  tile[r][q * 4 + 2] = fmaxf(v.z * aa.z + bb.z, 0.f);
  tile[r][q * 4 + 3] = fmaxf(v.w * aa.w + bb.w, 0.f);
  __syncthreads();
  float4 o = make_float4(tile[q * 4 + 0][r], tile[q * 4 + 1][r], tile[q * 4 + 2][r],
                         tile[q * 4 + 3][r]);
  *(float4*)(z + ((size_t)b * 128 + c0 + r) * NPTS + n0 + q * 4) = o;
}

// ---------------- eig pass 1: per-batch max d2, j-sliced for occupancy ----------------
// grid (NPTS/64, 8, NB); block 256 = 64 i x 4 j-subslices of a 512-pt slice
__global__ __launch_bounds__(256)
void maxd2_kernel(const float* __restrict__ pc, unsigned int* __restrict__ mx) {
  __shared__ float4 sp[512];
  __shared__ float lm[4];
  int b = blockIdx.z;
  int j0 = blockIdx.y * 512;
  int i0 = blockIdx.x * 64;
  const float* pb = pc + (size_t)b * NPTS * 3;
  for (int t = threadIdx.x; t < 512; t += 256) {
    int j = j0 + t;
    sp[t] = make_float4(pb[j * 3], pb[j * 3 + 1], pb[j * 3 + 2], 0.f);
  }
  __syncthreads();
  int il = threadIdx.x & 63, sl = threadIdx.x >> 6;
  int i = i0 + il;
  float xi = pb[i * 3], yi = pb[i * 3 + 1], zi = pb[i * 3 + 2];
  float x2i = xi * xi + yi * yi + zi * zi;
  float m = 0.f;
#pragma unroll 4
  for (int j = sl * 128, e = sl * 128 + 128; j < e; ++j) {
    float4 pj = sp[j];
    float x2j = pj.x * pj.x + pj.y * pj.y + pj.z * pj.z;
    float dot = xi * pj.x + yi * pj.y + zi * pj.z;
    float d2 = fmaxf(x2i + x2j - 2.f * dot, 0.f);  // d2(i,i)==0, can't be the max
    m = fmaxf(m, d2);
  }
#pragma unroll
  for (int off = 32; off > 0; off >>= 1) m = fmaxf(m, __shfl_xor(m, off, 64));
  int w = threadIdx.x >> 6;
  if ((threadIdx.x & 63) == 0) lm[w] = m;
  __syncthreads();
  if (threadIdx.x == 0) {
    float v = fmaxf(fmaxf(lm[0], lm[1]), fmaxf(lm[2], lm[3]));
    atomicMax(&mx[b], __float_as_uint(v));  // nonneg: bit order == value order
  }
}

// ---------------- eig pass 2a: masked-cov partial sums over a 1024-pt j-slice ---------
// grid (NPTS/32, 4, NB); block 256 = 32 i x 8 j-subslices (128 j each)
// partials: part[((b*4+js)*10+v)*NPTS + i]  (coalesced write/read)
__global__ __launch_bounds__(256)
void eigs_partial(const float* __restrict__ pc, const unsigned int* __restrict__ mx,
                  float* __restrict__ part) {
  __shared__ float4 sp[1024];
  __shared__ float red[4][32][10];
  int b = blockIdx.z;
  int js = blockIdx.y;
  int j0 = js * 1024;
  int i0 = blockIdx.x * 32;
  const float* pb = pc + (size_t)b * NPTS * 3;
  for (int t = threadIdx.x; t < 1024; t += 256) {
    int j = j0 + t;
    sp[t] = make_float4(pb[j * 3], pb[j * 3 + 1], pb[j * 3 + 2], 0.f);
  }
  __syncthreads();
  int il = threadIdx.x & 31, sl = threadIdx.x >> 5;
  int i = i0 + il;
  float xi = pb[i * 3], yi = pb[i * 3 + 1], zi = pb[i * 3 + 2];
  float x2i = xi * xi + yi * yi + zi * zi;
  float r2 = 0.01f * fmaxf(__uint_as_float(mx[b]), 1e-12f);
  float vals[10];
#pragma unroll
  for (int v = 0; v < 10; ++v) vals[v] = 0.f;
  int iloc = i - j0;  // local index of i within this slice (may be out of range)
#pragma unroll 2
  for (int j = sl * 128, e = sl * 128 + 128; j < e; ++j) {
    float4 pj = sp[j];
    float x2j = pj.x * pj.x + pj.y * pj.y + pj.z * pj.z;
    float dot = xi * pj.x + yi * pj.y + zi * pj.z;
    float d2 = fmaxf(x2i + x2j - 2.f * dot, 0.f);
    d2 = fmaxf(d2, 1e-12f);
    float msk = ((d2 < r2) && (j != iloc)) ? 1.f : 0.f;
    vals[0] += msk;
    vals[1] = fmaf(msk, pj.x, vals[1]);
    vals[2] = fmaf(msk, pj.y, vals[2]);
    vals[3] = fmaf(msk, pj.z, vals[3]);
    vals[4] = fmaf(msk, pj.x * pj.x, vals[4]);
    vals[5] = fmaf(msk, pj.x * pj.y, vals[5]);
    vals[6] = fmaf(msk, pj.x * pj.z, vals[6]);
    vals[7] = fmaf(msk, pj.y * pj.y, vals[7]);
    vals[8] = fmaf(msk, pj.y * pj.z, vals[8]);
    vals[9] = fmaf(msk, pj.z * pj.z, vals[9]);
  }
  // lanes 0-31 hold subslice 2w, lanes 32-63 subslice 2w+1: fold, then fold 4 waves
#pragma unroll
  for (int v = 0; v < 10; ++v) vals[v] += __shfl_xor(vals[v], 32, 64);
  int w = threadIdx.x >> 6;
  if ((threadIdx.x & 63) < 32)
#pragma unroll
    for (int v = 0; v < 10; ++v) red[w][il][v] = vals[v];
  __syncthreads();
  if (threadIdx.x < 32) {
    int ii = i0 + threadIdx.x;
    size_t base = ((size_t)(b * 4 + js) * 10) * NPTS + ii;
#pragma unroll
    for (int v = 0; v < 10; ++v)
      part[base + (size_t)v * NPTS] =
          red[0][threadIdx.x][v] + red[1][threadIdx.x][v] + red[2][threadIdx.x][v] +
          red[3][threadIdx.x][v];
  }
}

// ---------------- eig pass 2b: combine slices -> eigvals -> MLP -> Zt cols 160..163 ---
__global__ __launch_bounds__(256)
void eigs_finalize(const float* __restrict__ part, const float* __restrict__ ew1,
                   const float* __restrict__ eb1, const float* __restrict__ ew2,
                   const float* __restrict__ eb2, unsigned short* __restrict__ Zt) {
  int p = blockIdx.x * 256 + threadIdx.x;  // 0 .. NB*NPTS-1
  int b = p >> 12, i = p & (NPTS - 1);
  float t[10];
#pragma unroll
  for (int v = 0; v < 10; ++v) {
    float s = 0.f;
#pragma unroll
    for (int js = 0; js < 4; ++js)
      s += part[((size_t)(b * 4 + js) * 10 + v) * NPTS + i];
    t[v] = s;
  }
  double cntd = (double)t[0];
  double denom = cntd > 1.0 ? cntd : 1.0;
  double mux = t[1] / denom, muy = t[2] / denom, muz = t[3] / denom;
  const double inv_n = 1.0 / (double)NPTS;
  double a00 = ((double)t[4] - cntd * mux * mux) * inv_n;
  double a01 = ((double)t[5] - cntd * mux * muy) * inv_n;
  double a02 = ((double)t[6] - cntd * mux * muz) * inv_n;
  double a11 = ((double)t[7] - cntd * muy * muy) * inv_n;
  double a12 = ((double)t[8] - cntd * muy * muz) * inv_n;
  double a22 = ((double)t[9] - cntd * muz * muz) * inv_n;
  double e0, e1, e2;
  double p1 = a01 * a01 + a02 * a02 + a12 * a12;
  double q = (a00 + a11 + a22) / 3.0;
  double d0 = a00 - q, d1 = a11 - q, d2q = a22 - q;
  double p2 = d0 * d0 + d1 * d1 + d2q * d2q + 2.0 * p1;
  if (p2 <= 1e-30) {
    e0 = e1 = e2 = q;
  } else {
    double pp = sqrt(p2 / 6.0);
    double ip = 1.0 / pp;
    double b00 = d0 * ip, b11 = d1 * ip, b22 = d2q * ip;
    double b01 = a01 * ip, b02 = a02 * ip, b12 = a12 * ip;
    double detB = b00 * (b11 * b22 - b12 * b12) - b01 * (b01 * b22 - b12 * b02) +
                  b02 * (b01 * b12 - b11 * b02);
    double r = detB * 0.5;
    r = r < -1.0 ? -1.0 : (r > 1.0 ? 1.0 : r);
    double phi = acos(r) / 3.0;
    e2 = q + 2.0 * pp * cos(phi);
    e0 = q + 2.0 * pp * cos(phi + 2.0943951023931953);
    e1 = 3.0 * q - e0 - e2;
  }
  float eg[3] = {(float)e0, (float)e1, (float)e2};
  float tmp[4];
#pragma unroll
  for (int e = 0; e < 4; ++e) {
    float v = eb1[e];
#pragma unroll
    for (int k = 0; k < 3; ++k) v = fmaf(eg[k], ew1[k * 4 + e], v);
    tmp[e] = fmaxf(v, 0.f);
  }
  float h3[4];
#pragma unroll
  for (int f = 0; f < 4; ++f) {
    float v = eb2[f];
#pragma unroll
    for (int e = 0; e < 4; ++e) v = fmaf(tmp[e], ew2[e * 4 + f], v);
    h3[f] = v;
  }
  *(uint2*)(Zt + ((size_t)b * NPTS + i) * 192 + 160) = pack4(h3[0], h3[1], h3[2], h3[3]);
}

extern "C" void kernel_launch(void* const* d_in, const int* in_sizes, int n_in,
                              void* d_out, int out_size, void* d_ws, size_t ws_size,
                              hipStream_t stream) {
  (void)in_sizes; (void)n_in; (void)out_size; (void)ws_size;
  const float* pc    = (const float*)d_in[0];
  const float* h1    = (const float*)d_in[1];
  const float* h2    = (const float*)d_in[2];
  const float* dgw1  = (const float*)d_in[3];
  const float* dgg1  = (const float*)d_in[5];
  const float* dgbe1 = (const float*)d_in[6];
  const float* dgw2  = (const float*)d_in[7];
  const float* dgg2  = (const float*)d_in[9];
  const float* dgbe2 = (const float*)d_in[10];
  const float* dgw3  = (const float*)d_in[11];
  const float* dgg3  = (const float*)d_in[13];
  const float* dgbe3 = (const float*)d_in[14];
  const float* ew1   = (const float*)d_in[15];
  const float* eb1   = (const float*)d_in[16];
  const float* ew2   = (const float*)d_in[17];
  const float* eb2   = (const float*)d_in[18];
  const float* w1    = (const float*)d_in[19];
  const float* g1    = (const float*)d_in[21];
  const float* be1   = (const float*)d_in[22];
  const float* w2    = (const float*)d_in[23];
  const float* g2    = (const float*)d_in[25];
  const float* be2   = (const float*)d_in[26];
  const float* w3    = (const float*)d_in[27];
  const float* g3    = (const float*)d_in[29];
  const float* be3   = (const float*)d_in[30];
  float* out = (float*)d_out;

  // ---- workspace layout ----
  char* p = (char*)d_ws;
  auto take = [&](size_t bytes) { char* r = p; p += (bytes + 255) & ~(size_t)255; return r; };
  unsigned short* h2t = (unsigned short*)take((size_t)NB * NPTS * 1024 * 2);
  unsigned short* y1t = (unsigned short*)take((size_t)NB * NPTS * 256 * 2);
  unsigned short* y2t = (unsigned short*)take((size_t)NB * NPTS * 64 * 2);
  unsigned short* Zt  = (unsigned short*)take((size_t)NB * NPTS * 192 * 2);
  unsigned short* y4t = (unsigned short*)take((size_t)NB * NPTS * 512 * 2);
  unsigned short* y5t = (unsigned short*)take((size_t)NB * NPTS * 256 * 2);
  unsigned short* wp1 = (unsigned short*)take((size_t)256 * 1024 * 2);
  unsigned short* wp2 = (unsigned short*)take((size_t)64 * 256 * 2);
  unsigned short* wp3 = (unsigned short*)take((size_t)64 * 64 * 2);
  unsigned short* wp4 = (unsigned short*)take((size_t)512 * 192 * 2);
  unsigned short* wp5 = (unsigned short*)take((size_t)256 * 512 * 2);
  unsigned short* wp6 = (unsigned short*)take((size_t)128 * 256 * 2);
  float* Yf   = (float*)take((size_t)NB * NPTS * 512 * 4);
  float* psum = (float*)take((size_t)512 * 128 * 4);
  float* psq  = (float*)take((size_t)512 * 128 * 4);
  float* a_   = (float*)take((size_t)512 * 4);
  float* b_   = (float*)take((size_t)512 * 4);
  float* part = (float*)take((size_t)NB * 4 * 10 * NPTS * 4);
  unsigned int* mx = (unsigned int*)take(256);

  // ---- weight prep ----
  WArgs wa;
  wa.src[0] = dgw1; wa.dst[0] = wp1; wa.M[0] = 256; wa.K[0] = 1024; wa.Mp[0] = 256; wa.Kp[0] = 1024;
  wa.src[1] = dgw2; wa.dst[1] = wp2; wa.M[1] = 64;  wa.K[1] = 256;  wa.Mp[1] = 64;  wa.Kp[1] = 256;
  wa.src[2] = dgw3; wa.dst[2] = wp3; wa.M[2] = 32;  wa.K[2] = 64;   wa.Mp[2] = 64;  wa.Kp[2] = 64;
  wa.src[3] = w1;   wa.dst[3] = wp4; wa.M[3] = 512; wa.K[3] = 164;  wa.Mp[3] = 512; wa.Kp[3] = 192;
  wa.src[4] = w2;   wa.dst[4] = wp5; wa.M[4] = 256; wa.K[4] = 512;  wa.Mp[4] = 256; wa.Kp[4] = 512;
  wa.src[5] = w3;   wa.dst[5] = wp6; wa.M[5] = 128; wa.K[5] = 256;  wa.Mp[5] = 128; wa.Kp[5] = 256;
  prep_w<<<dim3(256, 6), 256, 0, stream>>>(wa);

  // ---- eig path first (independent; writes Zt cols 160..163) ----
  hipMemsetAsync(mx, 0, 2 * sizeof(unsigned int), stream);
  maxd2_kernel<<<dim3(NPTS / 64, 8, NB), 256, 0, stream>>>(pc, mx);
  eigs_partial<<<dim3(NPTS / 32, 4, NB), 256, 0, stream>>>(pc, mx, part);
  eigs_finalize<<<NB * NPTS / 256, 256, 0, stream>>>(part, ew1, eb1, ew2, eb2, Zt);

  // ---- input transposes: h2 -> h2t[b][n][1024]; h1 -> Zt cols 0..127; pad cols ----
  transpose_in<<<dim3(32, 128, NB), 256, 0, stream>>>(h2, 1024, h2t, 1024, 0);
  transpose_in<<<dim3(4, 128, NB), 256, 0, stream>>>(h1, 128, Zt, 192, 0);
  zero_z<<<224, 256, 0, stream>>>(Zt);

  auto layer = [&](const unsigned short* Wp, const unsigned short* X, int M, int Mp, int Kp,
                   const float* g, const float* be, unsigned short* dst, int dstStride,
                   int dstOff, int Mvalid) {
    dim3 grid(NPTS / 128, Mp / 64, NB);
    gemm_mfma<<<grid, 256, 0, stream>>>(Wp, X, Yf, psum, psq, M, Mp, Kp);
    bn_finalize<<<M, 128, 0, stream>>>(psum, psq, g, be, a_, b_);
    int tot = NB * NPTS * (Mvalid / 4);
    int blocks = (tot + 255) / 256;
    if (blocks > 2048) blocks = 2048;
    bn_apply_t<<<blocks, 256, 0, stream>>>(Yf, a_, b_, dst, Mp, Mvalid / 4, dstStride, dstOff);
  };

  // dg chain (conv biases cancel under BN mean subtraction)
  layer(wp1, h2t, 256, 256, 1024, dgg1, dgbe1, y1t, 256, 0, 256);
  layer(wp2, y1t, 64, 64, 256, dgg2, dgbe2, y2t, 64, 0, 64);
  layer(wp3, y2t, 32, 64, 64, dgg3, dgbe3, Zt, 192, 128, 32);  // f2 -> Zt cols 128..159

  // head chain
  layer(wp4, Zt, 512, 512, 192, g1, be1, y4t, 512, 0, 512);
  layer(wp5, y4t, 256, 256, 512, g2, be2, y5t, 256, 0, 256);
  {
    dim3 grid(NPTS / 128, 2, NB);
    gemm_mfma<<<grid, 256, 0, stream>>>(wp6, y5t, Yf, psum, psq, 128, 128, 256);
    bn_finalize<<<128, 128, 0, stream>>>(psum, psq, g3, be3, a_, b_);
    bn_out_t<<<dim3(4, 128, NB), 256, 0, stream>>>(Yf, a_, b_, out + (size_t)NB * NPTS * 3);
  }

  // output 0: xyz copy
  hipMemcpyAsync(d_out, d_in[0], (size_t)NB * NPTS * 3 * sizeof(float),
                 hipMemcpyDeviceToDevice, stream);
}

// Round 5
// 184.840 us; speedup vs baseline: 3.3239x; 1.0177x over previous
//
#include <hip/hip_runtime.h>
#include <math.h>

#define NPTS 4096
#define NB 2

typedef __attribute__((ext_vector_type(8))) short short8;
typedef __attribute__((ext_vector_type(4))) float f32x4;
typedef unsigned int uint32;

__device__ __forceinline__ unsigned short f2bf(float f) {
  uint32 u = __float_as_uint(f);
  uint32 r = (u + 0x7FFFu + ((u >> 16) & 1u)) >> 16;
  return (unsigned short)r;
}
__device__ __forceinline__ uint2 pack4(float a, float b, float c, float d) {
  uint2 r;
  r.x = (uint32)f2bf(a) | ((uint32)f2bf(b) << 16);
  r.y = (uint32)f2bf(c) | ((uint32)f2bf(d) << 16);
  return r;
}
__device__ __forceinline__ void gload16(const void* g, void* l) {
  __builtin_amdgcn_global_load_lds(
      (const __attribute__((address_space(1))) unsigned int*)g,
      (__attribute__((address_space(3))) unsigned int*)l, 16, 0, 0);
}

struct WArgs {
  const float* src[6];
  unsigned short* dst[6];
};

// ---------------- transpose tile helper: src[b][C][4096] f32 -> dst[b][n][dstOff+c] bf16
__device__ __forceinline__ void transpose_tile(const float* __restrict__ src, int C,
                                               unsigned short* __restrict__ dst,
                                               int dstStride, int dstOff, int b, int c0,
                                               int n0) {
  __shared__ float tile[32][33];
  const float* s = src + (size_t)b * C * NPTS;
  int r = threadIdx.x >> 3, q = threadIdx.x & 7;
  float4 v = *(const float4*)(s + (size_t)(c0 + r) * NPTS + n0 + q * 4);
  tile[r][q * 4 + 0] = v.x;
  tile[r][q * 4 + 1] = v.y;
  tile[r][q * 4 + 2] = v.z;
  tile[r][q * 4 + 3] = v.w;
  __syncthreads();
  uint2 o = pack4(tile[q * 4 + 0][r], tile[q * 4 + 1][r], tile[q * 4 + 2][r],
                  tile[q * 4 + 3][r]);
  *(uint2*)(dst + ((size_t)b * NPTS + n0 + r) * dstStride + dstOff + c0 + q * 4) = o;
}

// ---------------- mega prep: weights, h2 transpose, h1->Zt, zero pads, mx init -------
// blocks [0,8192): h2 transpose; [8192,9216): h1->Zt; [9216,9248): zero pads;
// [9248,9504): weight prep; [9504]: mx init
__global__ __launch_bounds__(256)
void prep_all(const float* __restrict__ h2, const float* __restrict__ h1, WArgs wa,
              unsigned short* __restrict__ h2t, unsigned short* __restrict__ Zt,
              unsigned int* __restrict__ mx) {
  int bid = blockIdx.x;
  if (bid < 8192) {
    int b = bid >> 12;
    int r = bid & 4095;
    int ct = r & 31, nt = r >> 5;
    transpose_tile(h2, 1024, h2t, 1024, 0, b, ct * 32, nt * 32);
  } else if (bid < 9216) {
    int r = bid - 8192;
    int b = r >> 9;
    int r2 = r & 511;
    int ct = r2 & 3, nt = r2 >> 2;
    transpose_tile(h1, 128, Zt, 192, 0, b, ct * 32, nt * 32);
  } else if (bid < 9248) {
    int r = bid - 9216;
    int tot = NB * NPTS * 7;
    for (int idx = r * 256 + threadIdx.x; idx < tot; idx += 32 * 256) {
      int u = idx % 7;
      int n = (idx / 7) & (NPTS - 1);
      int b = idx / (7 * NPTS);
      *(uint2*)(Zt + ((size_t)b * NPTS + n) * 192 + 164 + u * 4) = make_uint2(0u, 0u);
    }
  } else if (bid < 9504) {
    // weight prep, flat over all 6 (Mp*Kp) segments
    const int segMp[6] = {256, 64, 64, 512, 256, 128};
    const int segKp[6] = {1024, 256, 64, 192, 512, 256};
    const int segM[6] = {256, 64, 32, 512, 256, 128};
    const int segK[6] = {1024, 256, 64, 164, 512, 256};
    const int segEnd[6] = {262144, 278528, 282624, 380928, 512000, 544768};
    int r = bid - 9248;
    for (int idx = r * 256 + threadIdx.x; idx < 544768; idx += 256 * 256) {
      int w = 0, start = 0;
#pragma unroll
      for (int s = 0; s < 6; ++s)
        if (idx >= segEnd[s]) { w = s + 1; start = segEnd[s]; }
      int local = idx - start;
      int Kp = segKp[w];
      int m = local / Kp, k = local % Kp;
      float v = (m < segM[w] && k < segK[w]) ? wa.src[w][m * segK[w] + k] : 0.f;
      wa.dst[w][local] = f2bf(v);
    }
  } else {
    if (threadIdx.x < 2) mx[threadIdx.x] = 0u;
  }
}

// ---------------- MFMA GEMM: Yt[b][n][m] = sum_k Wp[m][k] * X[b][n][k]
// FUSED=0: X = bf16 activations, global_load_lds staging.
// FUSED=1: X = prev layer's raw f32 Yf; staging applies a*y+b, relu, -> bf16 (reg-staged).
// block tile 64(M) x 128(N), BK=64, 4 waves; LDS rows padded to 144B.
template <int FUSED>
__global__ __launch_bounds__(256)
void gemm_mfma_t(const unsigned short* __restrict__ Wp, const unsigned short* __restrict__ Xbf,
                 const float* __restrict__ Xf, const float* __restrict__ pa,
                 const float* __restrict__ pb, float* __restrict__ Yt,
                 float* __restrict__ psum, float* __restrict__ psq, int M, int Mp, int Kp) {
  __shared__ char smem[2][18432];  // 128 rows x 144B, x2
  __shared__ float a_sh[512], b_sh[512];
  const int b = blockIdx.z, nblk = blockIdx.x, mt = blockIdx.y;
  const int n0 = nblk * 128, m0 = mt * 64;
  const int tid = threadIdx.x, lane = tid & 63, wid = tid >> 6;
  const int wm = wid >> 1, wn = wid & 1;
  const int g = lane >> 4, c = lane & 15;
  const int ktiles = Kp >> 6;
  const unsigned short* Xb = Xbf + (size_t)b * NPTS * Kp;
  const float* Xfb = Xf + (size_t)b * NPTS * Kp;

  if (FUSED) {
    for (int t = tid; t < Kp; t += 256) {
      a_sh[t] = pa[t];
      b_sh[t] = pb[t];
    }
    __syncthreads();
  }

  // direct staging (async to LDS)
  auto stage_direct = [&](int buf, int t) {
    int k0 = t << 6;
#pragma unroll
    for (int i = 0; i < 5; ++i) {
      int u = tid + i * 256;
      if (u < 1152) {
        int n = u / 9, r9 = u % 9;
        int k = r9 < 8 ? r9 * 8 : 0;  // slot 8 = row pad (never read)
        gload16(Xb + (size_t)(n0 + n) * Kp + k0 + k, &smem[buf][u * 16]);
      }
    }
  };
  // fused staging: load f32 to regs
  float4 ld[5][2];
  auto stage_load = [&](int t) {
    int k0 = t << 6;
#pragma unroll
    for (int i = 0; i < 5; ++i) {
      int u = tid + i * 256;
      if (u < 1152) {
        int n = u / 9, r9 = u % 9;
        if (r9 < 8) {
          const float* src = Xfb + (size_t)(n0 + n) * Kp + k0 + r9 * 8;
          ld[i][0] = *(const float4*)src;
          ld[i][1] = *(const float4*)(src + 4);
        }
      }
    }
  };
  auto stage_write = [&](int buf, int t) {
    int k0 = t << 6;
#pragma unroll
    for (int i = 0; i < 5; ++i) {
      int u = tid + i * 256;
      if (u < 1152) {
        int r9 = u % 9;
        uint4 o = make_uint4(0u, 0u, 0u, 0u);
        if (r9 < 8) {
          int k = k0 + r9 * 8;
          float4 a0 = *(const float4*)&a_sh[k], a1 = *(const float4*)&a_sh[k + 4];
          float4 b0 = *(const float4*)&b_sh[k], b1 = *(const float4*)&b_sh[k + 4];
          uint2 lo = pack4(fmaxf(ld[i][0].x * a0.x + b0.x, 0.f),
                           fmaxf(ld[i][0].y * a0.y + b0.y, 0.f),
                           fmaxf(ld[i][0].z * a0.z + b0.z, 0.f),
                           fmaxf(ld[i][0].w * a0.w + b0.w, 0.f));
          uint2 hi = pack4(fmaxf(ld[i][1].x * a1.x + b1.x, 0.f),
                           fmaxf(ld[i][1].y * a1.y + b1.y, 0.f),
                           fmaxf(ld[i][1].z * a1.z + b1.z, 0.f),
                           fmaxf(ld[i][1].w * a1.w + b1.w, 0.f));
          o = make_uint4(lo.x, lo.y, hi.x, hi.y);
        }
        *(uint4*)&smem[buf][u * 16] = o;
      }
    }
  };
  auto loadA = [&](int t, uint4* A) {
    const unsigned short* base = Wp + (size_t)(m0 + wm * 32 + c) * Kp + (t << 6) + g * 8;
#pragma unroll
    for (int mf = 0; mf < 2; ++mf)
#pragma unroll
      for (int kw = 0; kw < 2; ++kw)
        A[mf * 2 + kw] = *(const uint4*)(base + (size_t)mf * 16 * Kp + kw * 32);
  };

  f32x4 acc[2][4] = {};
  uint4 Acur[4], Anext[4];
  if (FUSED) {
    stage_load(0);
    stage_write(0, 0);
  } else {
    stage_direct(0, 0);
  }
  loadA(0, Acur);
  __syncthreads();
  int cur = 0;

  for (int t = 0; t < ktiles; ++t) {
    if (t + 1 < ktiles) {
      if (FUSED) stage_load(t + 1);
      else stage_direct(cur ^ 1, t + 1);
      loadA(t + 1, Anext);
    }
#pragma unroll
    for (int kw = 0; kw < 2; ++kw) {
      union { uint4 u; short8 s; } a0, a1;
      a0.u = Acur[0 * 2 + kw];
      a1.u = Acur[1 * 2 + kw];
#pragma unroll
      for (int nf = 0; nf < 4; ++nf) {
        union { uint4 u; short8 s; } bf;
        bf.u = *(const uint4*)&smem[cur][(wn * 64 + nf * 16 + c) * 144 + kw * 64 + g * 16];
        acc[0][nf] = __builtin_amdgcn_mfma_f32_16x16x32_bf16(a0.s, bf.s, acc[0][nf], 0, 0, 0);
        acc[1][nf] = __builtin_amdgcn_mfma_f32_16x16x32_bf16(a1.s, bf.s, acc[1][nf], 0, 0, 0);
      }
    }
    if (FUSED && t + 1 < ktiles) stage_write(cur ^ 1, t + 1);
    __syncthreads();
    cur ^= 1;
#pragma unroll
    for (int i = 0; i < 4; ++i) Acur[i] = Anext[i];
  }

#pragma unroll
  for (int nf = 0; nf < 4; ++nf) {
    int n = n0 + wn * 64 + nf * 16 + c;
    float* yrow = Yt + ((size_t)b * NPTS + n) * Mp;
#pragma unroll
    for (int mf = 0; mf < 2; ++mf) {
      int mbase = m0 + wm * 32 + mf * 16 + g * 4;
      float4 v = make_float4(acc[mf][nf][0], acc[mf][nf][1], acc[mf][nf][2], acc[mf][nf][3]);
      *(float4*)(yrow + mbase) = v;
    }
  }
  int slot = (b * 32 + nblk) * 2 + wn;
#pragma unroll
  for (int mf = 0; mf < 2; ++mf)
#pragma unroll
    for (int r = 0; r < 4; ++r) {
      float s = 0.f, q = 0.f;
#pragma unroll
      for (int nf = 0; nf < 4; ++nf) {
        float v = acc[mf][nf][r];
        s += v;
        q += v * v;
      }
#pragma unroll
      for (int m = 1; m < 16; m <<= 1) {
        s += __shfl_xor(s, m, 64);
        q += __shfl_xor(q, m, 64);
      }
      int row = m0 + wm * 32 + mf * 16 + g * 4 + r;
      if (c == 0 && row < M) {
        psum[(size_t)row * 128 + slot] = s;
        psq[(size_t)row * 128 + slot] = q;
      }
    }
}

// ---------------- BN finalize: 128 slots -> a_[ch], b_[ch] ----------------
__global__ __launch_bounds__(128)
void bn_finalize(const float* __restrict__ psum, const float* __restrict__ psq,
                 const float* __restrict__ gamma, const float* __restrict__ beta,
                 float* __restrict__ a_, float* __restrict__ b_) {
  int ch = blockIdx.x, t = threadIdx.x;
  float s = psum[(size_t)ch * 128 + t];
  float q = psq[(size_t)ch * 128 + t];
#pragma unroll
  for (int m = 1; m < 64; m <<= 1) {
    s += __shfl_xor(s, m, 64);
    q += __shfl_xor(q, m, 64);
  }
  __shared__ float ws[2][2];
  if ((t & 63) == 0) { ws[t >> 6][0] = s; ws[t >> 6][1] = q; }
  __syncthreads();
  if (t == 0) {
    float S = ws[0][0] + ws[1][0];
    float Q = ws[0][1] + ws[1][1];
    const float inv = 1.f / (float)(NB * NPTS);
    float mean = S * inv;
    float var = Q * inv - mean * mean;
    if (var < 0.f) var = 0.f;
    float aa = rsqrtf(var + 1e-5f) * gamma[ch];
    a_[ch] = aa;
    b_[ch] = beta[ch] - mean * aa;
  }
}

// ---------------- f2 apply: BN(Yf3)[0..31] -> Zt cols 128..159 bf16 ----------------
__global__ __launch_bounds__(256)
void f2_apply(const float* __restrict__ Yt, const float* __restrict__ a_,
              const float* __restrict__ b_, unsigned short* __restrict__ Zt) {
  int idx = blockIdx.x * 256 + threadIdx.x;  // NB*NPTS*8
  int c4 = idx & 7;
  int n = (idx >> 3) & (NPTS - 1);
  int b = idx >> 15;
  float4 v = *(const float4*)(Yt + ((size_t)b * NPTS + n) * 64 + c4 * 4);
  float4 aa = ((const float4*)a_)[c4];
  float4 bb = ((const float4*)b_)[c4];
  uint2 o = pack4(fmaxf(v.x * aa.x + bb.x, 0.f), fmaxf(v.y * aa.y + bb.y, 0.f),
                  fmaxf(v.z * aa.z + bb.z, 0.f), fmaxf(v.w * aa.w + bb.w, 0.f));
  *(uint2*)(Zt + ((size_t)b * NPTS + n) * 192 + 128 + c4 * 4) = o;
}

// ---------------- final out: BN+transpose z, and xyz copy ----------------
// blocks [0,1024): z tiles; [1024,1048): xyz float4 copy
__global__ __launch_bounds__(256)
void out_final(const float* __restrict__ Yt, const float* __restrict__ a_,
               const float* __restrict__ b_, const float* __restrict__ pc,
               float* __restrict__ out) {
  int bid = blockIdx.x;
  if (bid < 1024) {
    __shared__ float tile[32][33];
    int b = bid >> 9;
    int r0 = bid & 511;
    int c0 = (r0 & 3) * 32, n0 = (r0 >> 2) * 32;
    int r = threadIdx.x >> 3, q = threadIdx.x & 7;
    float4 v = *(const float4*)(Yt + ((size_t)b * NPTS + n0 + r) * 128 + c0 + q * 4);
    float4 aa = *(const float4*)(a_ + c0 + q * 4);
    float4 bb = *(const float4*)(b_ + c0 + q * 4);
    tile[r][q * 4 + 0] = fmaxf(v.x * aa.x + bb.x, 0.f);
    tile[r][q * 4 + 1] = fmaxf(v.y * aa.y + bb.y, 0.f);
    tile[r][q * 4 + 2] = fmaxf(v.z * aa.z + bb.z, 0.f);
    tile[r][q * 4 + 3] = fmaxf(v.w * aa.w + bb.w, 0.f);
    __syncthreads();
    float4 o = make_float4(tile[q * 4 + 0][r], tile[q * 4 + 1][r], tile[q * 4 + 2][r],
                           tile[q * 4 + 3][r]);
    float* z = out + (size_t)NB * NPTS * 3;
    *(float4*)(z + ((size_t)b * 128 + c0 + r) * NPTS + n0 + q * 4) = o;
  } else {
    int i = (bid - 1024) * 256 + threadIdx.x;  // 6144 float4 = 24576 floats
    ((float4*)out)[i] = ((const float4*)pc)[i];
  }
}

// ---------------- eig pass 1: per-batch max d2, j-sliced ----------------
__global__ __launch_bounds__(256)
void maxd2_kernel(const float* __restrict__ pc, unsigned int* __restrict__ mx) {
  __shared__ float4 sp[512];
  __shared__ float lm[4];
  int b = blockIdx.z;
  int j0 = blockIdx.y * 512;
  int i0 = blockIdx.x * 64;
  const float* pb = pc + (size_t)b * NPTS * 3;
  for (int t = threadIdx.x; t < 512; t += 256) {
    int j = j0 + t;
    sp[t] = make_float4(pb[j * 3], pb[j * 3 + 1], pb[j * 3 + 2], 0.f);
  }
  __syncthreads();
  int il = threadIdx.x & 63, sl = threadIdx.x >> 6;
  int i = i0 + il;
  float xi = pb[i * 3], yi = pb[i * 3 + 1], zi = pb[i * 3 + 2];
  float x2i = xi * xi + yi * yi + zi * zi;
  float m = 0.f;
#pragma unroll 4
  for (int j = sl * 128, e = sl * 128 + 128; j < e; ++j) {
    float4 pj = sp[j];
    float x2j = pj.x * pj.x + pj.y * pj.y + pj.z * pj.z;
    float dot = xi * pj.x + yi * pj.y + zi * pj.z;
    float d2 = fmaxf(x2i + x2j - 2.f * dot, 0.f);
    m = fmaxf(m, d2);
  }
#pragma unroll
  for (int off = 32; off > 0; off >>= 1) m = fmaxf(m, __shfl_xor(m, off, 64));
  int w = threadIdx.x >> 6;
  if ((threadIdx.x & 63) == 0) lm[w] = m;
  __syncthreads();
  if (threadIdx.x == 0) {
    float v = fmaxf(fmaxf(lm[0], lm[1]), fmaxf(lm[2], lm[3]));
    atomicMax(&mx[b], __float_as_uint(v));
  }
}

// ---------------- eig pass 2a: masked-cov partials over 1024-pt j-slices -------------
__global__ __launch_bounds__(256)
void eigs_partial(const float* __restrict__ pc, const unsigned int* __restrict__ mx,
                  float* __restrict__ part) {
  __shared__ float4 sp[1024];
  __shared__ float red[4][32][10];
  int b = blockIdx.z;
  int js = blockIdx.y;
  int j0 = js * 1024;
  int i0 = blockIdx.x * 32;
  const float* pb = pc + (size_t)b * NPTS * 3;
  for (int t = threadIdx.x; t < 1024; t += 256) {
    int j = j0 + t;
    sp[t] = make_float4(pb[j * 3], pb[j * 3 + 1], pb[j * 3 + 2], 0.f);
  }
  __syncthreads();
  int il = threadIdx.x & 31, sl = threadIdx.x >> 5;
  int i = i0 + il;
  float xi = pb[i * 3], yi = pb[i * 3 + 1], zi = pb[i * 3 + 2];
  float x2i = xi * xi + yi * yi + zi * zi;
  float r2 = 0.01f * fmaxf(__uint_as_float(mx[b]), 1e-12f);
  float vals[10];
#pragma unroll
  for (int v = 0; v < 10; ++v) vals[v] = 0.f;
  int iloc = i - j0;
#pragma unroll 2
  for (int j = sl * 128, e = sl * 128 + 128; j < e; ++j) {
    float4 pj = sp[j];
    float x2j = pj.x * pj.x + pj.y * pj.y + pj.z * pj.z;
    float dot = xi * pj.x + yi * pj.y + zi * pj.z;
    float d2 = fmaxf(x2i + x2j - 2.f * dot, 0.f);
    d2 = fmaxf(d2, 1e-12f);
    float msk = ((d2 < r2) && (j != iloc)) ? 1.f : 0.f;
    vals[0] += msk;
    vals[1] = fmaf(msk, pj.x, vals[1]);
    vals[2] = fmaf(msk, pj.y, vals[2]);
    vals[3] = fmaf(msk, pj.z, vals[3]);
    vals[4] = fmaf(msk, pj.x * pj.x, vals[4]);
    vals[5] = fmaf(msk, pj.x * pj.y, vals[5]);
    vals[6] = fmaf(msk, pj.x * pj.z, vals[6]);
    vals[7] = fmaf(msk, pj.y * pj.y, vals[7]);
    vals[8] = fmaf(msk, pj.y * pj.z, vals[8]);
    vals[9] = fmaf(msk, pj.z * pj.z, vals[9]);
  }
#pragma unroll
  for (int v = 0; v < 10; ++v) vals[v] += __shfl_xor(vals[v], 32, 64);
  int w = threadIdx.x >> 6;
  if ((threadIdx.x & 63) < 32)
#pragma unroll
    for (int v = 0; v < 10; ++v) red[w][il][v] = vals[v];
  __syncthreads();
  if (threadIdx.x < 32) {
    int ii = i0 + threadIdx.x;
    size_t base = ((size_t)(b * 4 + js) * 10) * NPTS + ii;
#pragma unroll
    for (int v = 0; v < 10; ++v)
      part[base + (size_t)v * NPTS] =
          red[0][threadIdx.x][v] + red[1][threadIdx.x][v] + red[2][threadIdx.x][v] +
          red[3][threadIdx.x][v];
  }
}

// ---------------- eig pass 2b: combine -> eigvals -> MLP -> Zt cols 160..163 ---------
__global__ __launch_bounds__(256)
void eigs_finalize(const float* __restrict__ part, const float* __restrict__ ew1,
                   const float* __restrict__ eb1, const float* __restrict__ ew2,
                   const float* __restrict__ eb2, unsigned short* __restrict__ Zt) {
  int p = blockIdx.x * 256 + threadIdx.x;
  int b = p >> 12, i = p & (NPTS - 1);
  float t[10];
#pragma unroll
  for (int v = 0; v < 10; ++v) {
    float s = 0.f;
#pragma unroll
    for (int js = 0; js < 4; ++js)
      s += part[((size_t)(b * 4 + js) * 10 + v) * NPTS + i];
    t[v] = s;
  }
  double cntd = (double)t[0];
  double denom = cntd > 1.0 ? cntd : 1.0;
  double mux = t[1] / denom, muy = t[2] / denom, muz = t[3] / denom;
  const double inv_n = 1.0 / (double)NPTS;
  double a00 = ((double)t[4] - cntd * mux * mux) * inv_n;
  double a01 = ((double)t[5] - cntd * mux * muy) * inv_n;
  double a02 = ((double)t[6] - cntd * mux * muz) * inv_n;
  double a11 = ((double)t[7] - cntd * muy * muy) * inv_n;
  double a12 = ((double)t[8] - cntd * muy * muz) * inv_n;
  double a22 = ((double)t[9] - cntd * muz * muz) * inv_n;
  double e0, e1, e2;
  double p1 = a01 * a01 + a02 * a02 + a12 * a12;
  double q = (a00 + a11 + a22) / 3.0;
  double d0 = a00 - q, d1 = a11 - q, d2q = a22 - q;
  double p2 = d0 * d0 + d1 * d1 + d2q * d2q + 2.0 * p1;
  if (p2 <= 1e-30) {
    e0 = e1 = e2 = q;
  } else {
    double pp = sqrt(p2 / 6.0);
    double ip = 1.0 / pp;
    double b00 = d0 * ip, b11 = d1 * ip, b22 = d2q * ip;
    double b01 = a01 * ip, b02 = a02 * ip, b12 = a12 * ip;
    double detB = b00 * (b11 * b22 - b12 * b12) - b01 * (b01 * b22 - b12 * b02) +
                  b02 * (b01 * b12 - b11 * b02);
    double r = detB * 0.5;
    r = r < -1.0 ? -1.0 : (r > 1.0 ? 1.0 : r);
    double phi = acos(r) / 3.0;
    e2 = q + 2.0 * pp * cos(phi);
    e0 = q + 2.0 * pp * cos(phi + 2.0943951023931953);
    e1 = 3.0 * q - e0 - e2;
  }
  float eg[3] = {(float)e0, (float)e1, (float)e2};
  float tmp[4];
#pragma unroll
  for (int e = 0; e < 4; ++e) {
    float v = eb1[e];
#pragma unroll
    for (int k = 0; k < 3; ++k) v = fmaf(eg[k], ew1[k * 4 + e], v);
    tmp[e] = fmaxf(v, 0.f);
  }
  float h3[4];
#pragma unroll
  for (int f = 0; f < 4; ++f) {
    float v = eb2[f];
#pragma unroll
    for (int e = 0; e < 4; ++e) v = fmaf(tmp[e], ew2[e * 4 + f], v);
    h3[f] = v;
  }
  *(uint2*)(Zt + ((size_t)b * NPTS + i) * 192 + 160) = pack4(h3[0], h3[1], h3[2], h3[3]);
}

extern "C" void kernel_launch(void* const* d_in, const int* in_sizes, int n_in,
                              void* d_out, int out_size, void* d_ws, size_t ws_size,
                              hipStream_t stream) {
  (void)in_sizes; (void)n_in; (void)out_size; (void)ws_size;
  const float* pc    = (const float*)d_in[0];
  const float* h1    = (const float*)d_in[1];
  const float* h2    = (const float*)d_in[2];
  const float* dgw1  = (const float*)d_in[3];
  const float* dgg1  = (const float*)d_in[5];
  const float* dgbe1 = (const float*)d_in[6];
  const float* dgw2  = (const float*)d_in[7];
  const float* dgg2  = (const float*)d_in[9];
  const float* dgbe2 = (const float*)d_in[10];
  const float* dgw3  = (const float*)d_in[11];
  const float* dgg3  = (const float*)d_in[13];
  const float* dgbe3 = (const float*)d_in[14];
  const float* ew1   = (const float*)d_in[15];
  const float* eb1   = (const float*)d_in[16];
  const float* ew2   = (const float*)d_in[17];
  const float* eb2   = (const float*)d_in[18];
  const float* w1    = (const float*)d_in[19];
  const float* g1    = (const float*)d_in[21];
  const float* be1   = (const float*)d_in[22];
  const float* w2    = (const float*)d_in[23];
  const float* g2    = (const float*)d_in[25];
  const float* be2   = (const float*)d_in[26];
  const float* w3    = (const float*)d_in[27];
  const float* g3    = (const float*)d_in[29];
  const float* be3   = (const float*)d_in[30];
  float* out = (float*)d_out;

  // ---- workspace ----
  char* p = (char*)d_ws;
  auto take = [&](size_t bytes) { char* r = p; p += (bytes + 255) & ~(size_t)255; return r; };
  unsigned short* h2t = (unsigned short*)take((size_t)NB * NPTS * 1024 * 2);
  unsigned short* Zt  = (unsigned short*)take((size_t)NB * NPTS * 192 * 2);
  unsigned short* wp1 = (unsigned short*)take((size_t)256 * 1024 * 2);
  unsigned short* wp2 = (unsigned short*)take((size_t)64 * 256 * 2);
  unsigned short* wp3 = (unsigned short*)take((size_t)64 * 64 * 2);
  unsigned short* wp4 = (unsigned short*)take((size_t)512 * 192 * 2);
  unsigned short* wp5 = (unsigned short*)take((size_t)256 * 512 * 2);
  unsigned short* wp6 = (unsigned short*)take((size_t)128 * 256 * 2);
  float* YfA  = (float*)take((size_t)NB * NPTS * 512 * 4);
  float* YfB  = (float*)take((size_t)NB * NPTS * 512 * 4);
  float* psum = (float*)take((size_t)512 * 128 * 4);
  float* psq  = (float*)take((size_t)512 * 128 * 4);
  float* a_   = (float*)take((size_t)512 * 4);
  float* b_   = (float*)take((size_t)512 * 4);
  float* part = (float*)take((size_t)NB * 4 * 10 * NPTS * 4);
  unsigned int* mx = (unsigned int*)take(256);

  WArgs wa;
  wa.src[0] = dgw1; wa.dst[0] = wp1;
  wa.src[1] = dgw2; wa.dst[1] = wp2;
  wa.src[2] = dgw3; wa.dst[2] = wp3;
  wa.src[3] = w1;   wa.dst[3] = wp4;
  wa.src[4] = w2;   wa.dst[4] = wp5;
  wa.src[5] = w3;   wa.dst[5] = wp6;

  // 1: all prep (weights, transposes, pads, mx=0)
  prep_all<<<9505, 256, 0, stream>>>(h2, h1, wa, h2t, Zt, mx);
  // 2-4: eig path
  maxd2_kernel<<<dim3(NPTS / 64, 8, NB), 256, 0, stream>>>(pc, mx);
  eigs_partial<<<dim3(NPTS / 32, 4, NB), 256, 0, stream>>>(pc, mx, part);
  eigs_finalize<<<NB * NPTS / 256, 256, 0, stream>>>(part, ew1, eb1, ew2, eb2, Zt);

  auto gemmD = [&](const unsigned short* Wp, const unsigned short* X, float* Y, int M,
                   int Mp, int Kp, const float* g, const float* be) {
    dim3 grid(NPTS / 128, Mp / 64, NB);
    gemm_mfma_t<0><<<grid, 256, 0, stream>>>(Wp, X, YfA, a_, b_, Y, psum, psq, M, Mp, Kp);
    bn_finalize<<<M, 128, 0, stream>>>(psum, psq, g, be, a_, b_);
  };
  auto gemmF = [&](const unsigned short* Wp, const float* Xf, float* Y, int M, int Mp,
                   int Kp, const float* g, const float* be) {
    dim3 grid(NPTS / 128, Mp / 64, NB);
    gemm_mfma_t<1><<<grid, 256, 0, stream>>>(Wp, h2t, Xf, a_, b_, Y, psum, psq, M, Mp, Kp);
    bn_finalize<<<M, 128, 0, stream>>>(psum, psq, g, be, a_, b_);
  };

  // dg chain (conv biases cancel under BN mean subtraction)
  gemmD(wp1, h2t, YfA, 256, 256, 1024, dgg1, dgbe1);        // L1: h2t -> YfA
  gemmF(wp2, YfA, YfB, 64, 64, 256, dgg2, dgbe2);           // L2: BN(YfA) -> YfB
  gemmF(wp3, YfB, YfA, 32, 64, 64, dgg3, dgbe3);            // L3: BN(YfB) -> YfA
  f2_apply<<<NB * NPTS * 8 / 256, 256, 0, stream>>>(YfA, a_, b_, Zt);  // f2 -> Zt
  // head chain
  gemmD(wp4, Zt, YfB, 512, 512, 192, g1, be1);              // L4: Zt -> YfB
  gemmF(wp5, YfB, YfA, 256, 256, 512, g2, be2);             // L5
  gemmF(wp6, YfA, YfB, 128, 128, 256, g3, be3);             // L6
  out_final<<<1048, 256, 0, stream>>>(YfB, a_, b_, pc, out);
}